// Round 6
// baseline (537.683 us; speedup 1.0000x reference)
//
#include <hip/hip_runtime.h>
#include <hip/hip_bf16.h>
#include <cstdint>
#include <cstddef>

// Problem constants (match reference)
#define NN      50000
#define IN_C    512
#define EE      800000
#define ETOT    850000      // E + N self-loops
#define HH      2
#define CC      64
#define HC      128
#define BB      64
#define OUTC    2
#define NEG_SLOPE 0.2f
#define BN_EPS  1e-5f

#define NBLK_SCAN ((NN + 255) / 256)   // 196

// XCD binning for CSR build: 8 dst ranges, blockIdx%8 -> XCD (round-robin dispatch)
#define NXCD     8
#define NPX      ((NN + NXCD - 1) / NXCD)        // 6250 nodes per bin
#define EDGES_PER_SLOT 2048
#define NSLOT    ((ETOT + EDGES_PER_SLOT - 1) / EDGES_PER_SLOT)  // 416

typedef __bf16 bf16x8 __attribute__((ext_vector_type(8)));
typedef float  f32x4  __attribute__((ext_vector_type(4)));

__device__ __forceinline__ unsigned f2bf(float f) {
    __bf16 b = (__bf16)f;                      // RNE convert
    return (unsigned)__builtin_bit_cast(unsigned short, b);
}

// async global->LDS, 16B per lane; LDS dest is wave-uniform base + lane*16
__device__ __forceinline__ void gload_lds16(const float* g, float* l) {
    __builtin_amdgcn_global_load_lds(
        (const __attribute__((address_space(1))) unsigned*)g,
        (__attribute__((address_space(3))) unsigned*)l,
        16, 0, 0);
}

// ================= CSR build (XCD-binned: each XCD owns a dst range; atomics and
// esrc writes stay in one L2 — no cross-XCD line ping-pong / write amplification) ==========
__global__ __launch_bounds__(256) void deg_kernel(const int* __restrict__ ei, int* __restrict__ deg)
{
    const int xcd  = blockIdx.x & (NXCD - 1);
    const int slot = blockIdx.x >> 3;
    const int lo = xcd * NPX, hi = lo + NPX;
    const int base = slot * EDGES_PER_SLOT;
#pragma unroll
    for (int it = 0; it < EDGES_PER_SLOT / 256; ++it) {
        int e = base + it * 256 + threadIdx.x;
        if (e < ETOT) {
            int d = (e < EE) ? ei[EE + e] : (e - EE);
            if (d >= lo && d < hi) atomicAdd(&deg[d], 1);
        }
    }
}

// ================= fused single-kernel prefix scan (replaces bsum/bscan/bapply) ========
// One block, 256 threads, 196 chunks. Per chunk: wave __shfl_up inclusive scan +
// per-thread register carry (no global round-trips, 2 barriers/iter). Memory latency
// hidden by a 4-deep register prefetch pipeline (chunk c+4 issued while scanning c).
__global__ __launch_bounds__(256) void scan_kernel(
    const int* __restrict__ deg, int* __restrict__ rowp, int* __restrict__ cur)
{
    const int tid  = threadIdx.x;
    const int lane = tid & 63, wv = tid >> 6;
    __shared__ int wsum[4];
    int carry = 0;                       // per-thread running total of prior chunks

    int pre[4];
#pragma unroll
    for (int d = 0; d < 4; ++d) {
        int i = d * 256 + tid;
        pre[d] = (i < NN) ? deg[i] : 0;
    }

    for (int c = 0; c < NBLK_SCAN; ++c) {
        int v = pre[c & 3];
        int ni = (c + 4) * 256 + tid;
        if (c + 4 < NBLK_SCAN) pre[c & 3] = (ni < NN) ? deg[ni] : 0;

        // wave inclusive scan
        int x = v;
#pragma unroll
        for (int o = 1; o < 64; o <<= 1) {
            int y = __shfl_up(x, o);
            if (lane >= o) x += y;
        }
        if (lane == 63) wsum[wv] = x;
        __syncthreads();
        int s0 = wsum[0], s1 = wsum[1], s2 = wsum[2], s3 = wsum[3];
        int wo = carry;
        if (wv > 0) wo += s0;
        if (wv > 1) wo += s1;
        if (wv > 2) wo += s2;
        int i = c * 256 + tid;
        if (i < NN) {
            int r = wo + x - v;          // exclusive prefix
            rowp[i] = r; cur[i] = r;
        }
        carry += s0 + s1 + s2 + s3;
        __syncthreads();                 // protect wsum for next iteration
    }
    if (tid == 0) rowp[NN] = ETOT;
}

__global__ __launch_bounds__(256) void scatter_kernel(
    const int* __restrict__ ei, int* __restrict__ cur, int* __restrict__ esrc)
{
    const int xcd  = blockIdx.x & (NXCD - 1);
    const int slot = blockIdx.x >> 3;
    const int lo = xcd * NPX, hi = lo + NPX;
    const int base = slot * EDGES_PER_SLOT;
#pragma unroll
    for (int it = 0; it < EDGES_PER_SLOT / 256; ++it) {
        int e = base + it * 256 + threadIdx.x;
        if (e < ETOT) {
            int s, d;
            if (e < EE) { s = ei[e]; d = ei[EE + e]; }
            else        { s = e - EE; d = s; }
            if (d >= lo && d < hi) {
                int pos = atomicAdd(&cur[d], 1);
                esrc[pos] = s;
            }
        }
    }
}

// ================= W -> bf16 MFMA fragment order (both weights in one launch) ========
__global__ __launch_bounds__(256) void wfrag_kernel(
    const float* __restrict__ W1, unsigned short* __restrict__ Wf1,
    const float* __restrict__ W2, unsigned short* __restrict__ Wf2)
{
    int t = blockIdx.x * 256 + threadIdx.x;
    const float* W; unsigned short* Wf;
    if (t < IN_C * 16) { W = W1; Wf = Wf1; }
    else {
        t -= IN_C * 16;
        if (t >= HC * 16) return;
        W = W2; Wf = Wf2;
    }
    int lane = t & 63, frag = t >> 6;
    int kblk = frag >> 3, nt = frag & 7;
    int quad = lane >> 4, ln = lane & 15;
    int kbase = kblk * 32 + quad * 8;
    int n = nt * 16 + ln;
    unsigned short u[8];
#pragma unroll
    for (int j = 0; j < 8; ++j)
        u[j] = (unsigned short)f2bf(W[(size_t)(kbase + j) * HC + n]);
    ushort4 a; a.x = u[0]; a.y = u[1]; a.z = u[2]; a.w = u[3];
    ushort4 b; b.x = u[4]; b.y = u[5]; b.z = u[6]; b.w = u[7];
    *(ushort4*)(Wf + (size_t)t * 8)     = a;
    *(ushort4*)(Wf + (size_t)t * 8 + 4) = b;
}

// ================= LDS-staged MFMA GEMM, BK=64 per barrier (R4-measured form) =========
// Block = 64 rows x 128 cols, 4 waves. A staged via global_load_lds into a 2 x 16 KB
// double buffer, TWO 32-wide K-substeps per barrier. LDS sub-tile [64][32] XOR-swizzled
// via pre-swizzled global source (rule 21). B streamed from L2 in regs, double-buffered.
template<int K, bool AFFINE>
__global__ __launch_bounds__(256) void mfma_gemm_kernel(
    const float* __restrict__ A, const unsigned short* __restrict__ Wf,
    const float* __restrict__ atts, const float* __restrict__ attd,
    unsigned* __restrict__ hb, float* __restrict__ as_, float* __restrict__ ad_,
    const float* __restrict__ sc, const float* __restrict__ sh)
{
    constexpr int NSTEP = K >> 5;                   // 32-wide substeps
    __shared__ __align__(16) float Abuf[2][64 * 64]; // 2 x 16 KB

    const int tid  = threadIdx.x;
    const int wave = tid >> 6, lane = tid & 63;
    const int quad = lane >> 4, ln = lane & 15;
    const int m0 = blockIdx.x * 64;

    // staging geometry: thread t covers 16B slot (row t>>3, slot t&7), rows +0/+32
    const int srow = tid >> 3;
    const int g    = (tid & 7) ^ (srow & 7);        // swizzled source slot
    int grow0 = m0 + srow;      if (grow0 > NN - 1) grow0 = NN - 1;
    int grow1 = m0 + srow + 32; if (grow1 > NN - 1) grow1 = NN - 1;
    const float* gsrc0 = A + (size_t)grow0 * K + g * 4;
    const float* gsrc1 = A + (size_t)grow1 * K + g * 4;

    // fragment-read geometry
    const int rr = wave * 16 + ln;
    const int base_f = rr * 32;
    const int sA = (((quad * 2)     ^ (rr & 7)) * 4);
    const int sB = (((quad * 2 + 1) ^ (rr & 7)) * 4);

    const unsigned short* wbase = Wf + lane * 8;

    f32x4 acc[8];
#pragma unroll
    for (int nt = 0; nt < 8; ++nt) acc[nt] = (f32x4){0.f, 0.f, 0.f, 0.f};

    // prologue: stage substeps 0,1 into buf0; load B frags for ks=0
    gload_lds16(gsrc0,      &Abuf[0][wave * 256]);
    gload_lds16(gsrc1,      &Abuf[0][1024 + wave * 256]);
    gload_lds16(gsrc0 + 32, &Abuf[0][2048 + wave * 256]);
    gload_lds16(gsrc1 + 32, &Abuf[0][3072 + wave * 256]);
    bf16x8 bfr[2][8];
#pragma unroll
    for (int nt = 0; nt < 8; ++nt) bfr[0][nt] = *(const bf16x8*)(wbase + nt * 512);

#pragma unroll
    for (int ks = 0; ks < NSTEP; ++ks) {
        const int sub  = ks & 1;             // substep within BK=64
        const int cbuf = (ks >> 1) & 1;      // LDS buffer
        const int bsel = ks & 1;             // rolling B-frag buffer
        if (sub == 0) {
            // barrier drains vmcnt(0): stage(kb) loads issued a full BK-iter ago are in
            __syncthreads();
            if (ks + 2 < NSTEP) {
                const float* n0 = gsrc0 + (size_t)(ks + 2) * 32;
                const float* n1 = gsrc1 + (size_t)(ks + 2) * 32;
                float* db = &Abuf[cbuf ^ 1][wave * 256];
                gload_lds16(n0,      db);
                gload_lds16(n1,      db + 1024);
                gload_lds16(n0 + 32, db + 2048);
                gload_lds16(n1 + 32, db + 3072);
            }
        }

        const float* fb_base = &Abuf[cbuf][sub * 2048 + base_f];
        float4 fa = *(const float4*)(fb_base + sA);
        float4 fb = *(const float4*)(fb_base + sB);
        float va[8] = {fa.x, fa.y, fa.z, fa.w, fb.x, fb.y, fb.z, fb.w};
        if (AFFINE) {
            const int kk = ks * 32 + quad * 8;
            const float4 s0 = *(const float4*)(sc + kk), s1 = *(const float4*)(sc + kk + 4);
            const float4 h0 = *(const float4*)(sh + kk), h1 = *(const float4*)(sh + kk + 4);
            va[0] = fmaxf(fmaf(s0.x, va[0], h0.x), 0.f);
            va[1] = fmaxf(fmaf(s0.y, va[1], h0.y), 0.f);
            va[2] = fmaxf(fmaf(s0.z, va[2], h0.z), 0.f);
            va[3] = fmaxf(fmaf(s0.w, va[3], h0.w), 0.f);
            va[4] = fmaxf(fmaf(s1.x, va[4], h1.x), 0.f);
            va[5] = fmaxf(fmaf(s1.y, va[5], h1.y), 0.f);
            va[6] = fmaxf(fmaf(s1.z, va[6], h1.z), 0.f);
            va[7] = fmaxf(fmaf(s1.w, va[7], h1.w), 0.f);
        }
        union { bf16x8 v; unsigned short u[8]; } af;
#pragma unroll
        for (int j = 0; j < 8; ++j) af.u[j] = (unsigned short)f2bf(va[j]);

        // prefetch next substep's B-frags (L2-hot; in flight across this step's MFMAs)
        if (ks + 1 < NSTEP) {
            const unsigned short* wfp = wbase + (size_t)(ks + 1) * 4096;
#pragma unroll
            for (int nt = 0; nt < 8; ++nt)
                bfr[bsel ^ 1][nt] = *(const bf16x8*)(wfp + nt * 512);
        }

#pragma unroll
        for (int nt = 0; nt < 8; ++nt)
            acc[nt] = __builtin_amdgcn_mfma_f32_16x16x32_bf16(af.v, bfr[bsel][nt], acc[nt], 0, 0, 0);
    }

    // epilogue: pack bf16 pairs + fused attention logits; C/D layout col=ln, row=quad*4+r
    float wsv[8], wdv[8];
#pragma unroll
    for (int nt = 0; nt < 8; ++nt) { wsv[nt] = atts[nt * 16 + ln]; wdv[nt] = attd[nt * 16 + ln]; }

    const int mbase = m0 + wave * 16 + quad * 4;
#pragma unroll
    for (int r = 0; r < 4; ++r) {
        int m = mbase + r;
        bool ok = (m < NN);
        float ps0 = 0.f, ps1 = 0.f, pd0 = 0.f, pd1 = 0.f;
#pragma unroll
        for (int nt = 0; nt < 8; ++nt) {
            float v = acc[nt][r];
            if (nt < 4) { ps0 = fmaf(v, wsv[nt], ps0); pd0 = fmaf(v, wdv[nt], pd0); }
            else        { ps1 = fmaf(v, wsv[nt], ps1); pd1 = fmaf(v, wdv[nt], pd1); }
        }
#pragma unroll
        for (int nt = 0; nt < 4; ++nt) {
            unsigned pk = f2bf(acc[nt][r]) | (f2bf(acc[nt + 4][r]) << 16);
            if (ok) hb[(size_t)m * 64 + nt * 16 + ln] = pk;
        }
#pragma unroll
        for (int o = 8; o > 0; o >>= 1) {
            ps0 += __shfl_down(ps0, o); ps1 += __shfl_down(ps1, o);
            pd0 += __shfl_down(pd0, o); pd1 += __shfl_down(pd1, o);
        }
        if (ok && ln == 0) {
            *(float2*)&as_[m * 2] = make_float2(ps0, ps1);
            *(float2*)&ad_[m * 2] = make_float2(pd0, pd1);
        }
    }
}

// ================= fused segment-softmax + aggregate + BN-stats partials =============
// One wave per dst node. Gather loop unrolled 8-deep (R4-measured form).
__global__ __launch_bounds__(256) void gat_agg_kernel(
    const int* __restrict__ rowp, const int* __restrict__ esrc,
    const float* __restrict__ as_, const float* __restrict__ ad_,
    const unsigned* __restrict__ hb, float* __restrict__ out,
    float* __restrict__ stats)
{
    const int tid  = threadIdx.x;
    const int node = (blockIdx.x * 256 + tid) >> 6;
    const int wave = tid >> 6;
    const int lane = tid & 63;
    int beg = rowp[node], end = rowp[node + 1];
    float2 adv = *(const float2*)&ad_[node * 2];

    float l0 = 0.f, l1 = 0.f, a0 = 0.f, a1 = 0.f;

    for (int j0 = beg; j0 < end; j0 += 64) {
        int nj = min(64, end - j0);
        int   sl  = 0;
        float p0l = 0.f, p1l = 0.f;
        if (j0 + lane < end) {
            sl = esrc[j0 + lane];
            float2 t = *(const float2*)&as_[sl * 2];
            float e0 = t.x + adv.x; e0 = fmaxf(e0, NEG_SLOPE * e0);
            float e1 = t.y + adv.y; e1 = fmaxf(e1, NEG_SLOPE * e1);
            p0l = __expf(e0); p1l = __expf(e1);
        }
        l0 += p0l; l1 += p1l;          // per-lane partial denominator

        int j = 0;
        for (; j + 8 <= nj; j += 8) {
            int s0 = __shfl(sl, j),     s1 = __shfl(sl, j + 1);
            int s2 = __shfl(sl, j + 2), s3 = __shfl(sl, j + 3);
            int s4 = __shfl(sl, j + 4), s5 = __shfl(sl, j + 5);
            int s6 = __shfl(sl, j + 6), s7 = __shfl(sl, j + 7);
            unsigned u0 = hb[(size_t)s0 * 64 + lane];
            unsigned u1 = hb[(size_t)s1 * 64 + lane];
            unsigned u2 = hb[(size_t)s2 * 64 + lane];
            unsigned u3 = hb[(size_t)s3 * 64 + lane];
            unsigned u4 = hb[(size_t)s4 * 64 + lane];
            unsigned u5 = hb[(size_t)s5 * 64 + lane];
            unsigned u6 = hb[(size_t)s6 * 64 + lane];
            unsigned u7 = hb[(size_t)s7 * 64 + lane];
            a0 = fmaf(__shfl(p0l, j    ), __uint_as_float(u0 << 16), a0);
            a1 = fmaf(__shfl(p1l, j    ), __uint_as_float(u0 & 0xffff0000u), a1);
            a0 = fmaf(__shfl(p0l, j + 1), __uint_as_float(u1 << 16), a0);
            a1 = fmaf(__shfl(p1l, j + 1), __uint_as_float(u1 & 0xffff0000u), a1);
            a0 = fmaf(__shfl(p0l, j + 2), __uint_as_float(u2 << 16), a0);
            a1 = fmaf(__shfl(p1l, j + 2), __uint_as_float(u2 & 0xffff0000u), a1);
            a0 = fmaf(__shfl(p0l, j + 3), __uint_as_float(u3 << 16), a0);
            a1 = fmaf(__shfl(p1l, j + 3), __uint_as_float(u3 & 0xffff0000u), a1);
            a0 = fmaf(__shfl(p0l, j + 4), __uint_as_float(u4 << 16), a0);
            a1 = fmaf(__shfl(p1l, j + 4), __uint_as_float(u4 & 0xffff0000u), a1);
            a0 = fmaf(__shfl(p0l, j + 5), __uint_as_float(u5 << 16), a0);
            a1 = fmaf(__shfl(p1l, j + 5), __uint_as_float(u5 & 0xffff0000u), a1);
            a0 = fmaf(__shfl(p0l, j + 6), __uint_as_float(u6 << 16), a0);
            a1 = fmaf(__shfl(p1l, j + 6), __uint_as_float(u6 & 0xffff0000u), a1);
            a0 = fmaf(__shfl(p0l, j + 7), __uint_as_float(u7 << 16), a0);
            a1 = fmaf(__shfl(p1l, j + 7), __uint_as_float(u7 & 0xffff0000u), a1);
        }
        for (; j + 2 <= nj; j += 2) {
            int sA = __shfl(sl, j), sB = __shfl(sl, j + 1);
            unsigned uA = hb[(size_t)sA * 64 + lane];
            unsigned uB = hb[(size_t)sB * 64 + lane];
            a0 = fmaf(__shfl(p0l, j    ), __uint_as_float(uA << 16), a0);
            a1 = fmaf(__shfl(p1l, j    ), __uint_as_float(uA & 0xffff0000u), a1);
            a0 = fmaf(__shfl(p0l, j + 1), __uint_as_float(uB << 16), a0);
            a1 = fmaf(__shfl(p1l, j + 1), __uint_as_float(uB & 0xffff0000u), a1);
        }
        if (j < nj) {
            int s = __shfl(sl, j);
            unsigned u = hb[(size_t)s * 64 + lane];
            a0 = fmaf(__shfl(p0l, j), __uint_as_float(u << 16), a0);
            a1 = fmaf(__shfl(p1l, j), __uint_as_float(u & 0xffff0000u), a1);
        }
    }

#pragma unroll
    for (int o = 1; o < 64; o <<= 1) {
        l0 += __shfl_xor(l0, o); l1 += __shfl_xor(l1, o);
    }
    float v0 = a0 / l0;
    float v1 = a1 / l1;
    out[(size_t)node * HC + lane]      = v0;
    out[(size_t)node * HC + 64 + lane] = v1;

    // ---- fused BN-stats partials ----
    __shared__ float red[4][256];
    red[wave][lane]      = v0;
    red[wave][64 + lane] = v1;
    __syncthreads();
    if (tid < 128) {
        float s = 0.f, q = 0.f;
#pragma unroll
        for (int w = 0; w < 4; ++w) {
            float v = red[w][tid];
            s += v; q = fmaf(v, v, q);
        }
        int slot = blockIdx.x & 63;
        atomicAdd(&stats[slot * 128 + tid], s);
        atomicAdd(&stats[64 * 128 + slot * 128 + tid], q);
    }
}

// ================= BN params: reduce 64 stat slices =================
__global__ void bn_params_kernel(
    const float* __restrict__ stats, const float* __restrict__ gamma,
    const float* __restrict__ beta, float* __restrict__ sc, float* __restrict__ sh)
{
    int c = threadIdx.x;                  // 128 threads
    float su = 0.f, sq = 0.f;
#pragma unroll
    for (int k = 0; k < 64; ++k) {
        su += stats[k * 128 + c];
        sq += stats[64 * 128 + k * 128 + c];
    }
    const float inv_n = 1.0f / (float)NN;
    float mu = su * inv_n;
    float var = sq * inv_n - mu * mu;
    float rs = rsqrtf(var + BN_EPS);
    float s = gamma[c] * rs;
    sc[c] = s;
    sh[c] = beta[c] - mu * s;
}

// ================= pool: 64 rows/block (782 blocks), flush-on-graph-change =================
__global__ __launch_bounds__(256) void pool_kernel(
    const float* __restrict__ x, const float* __restrict__ sc,
    const float* __restrict__ sh, const int* __restrict__ batch,
    float* __restrict__ pool, float* __restrict__ cnt)
{
    int c = threadIdx.x & 127;
    int half = threadIdx.x >> 7;
    int r0 = blockIdx.x * 64;
    int rend = min(r0 + 64, NN);
    float s = sc[c], b = sh[c];
    int cur = -1; float acc = 0.f, ccount = 0.f;
    for (int r = r0 + half; r < rend; r += 2) {
        int g = batch[r];
        if (g != cur) {
            if (cur >= 0) {
                atomicAdd(&pool[cur * HC + c], acc);
                if (c == 0) atomicAdd(&cnt[cur], ccount);
            }
            cur = g; acc = 0.f; ccount = 0.f;
        }
        float v = x[(size_t)r * HC + c];
        acc += fmaxf(fmaf(s, v, b), 0.f);
        ccount += 1.f;
    }
    if (cur >= 0) {
        atomicAdd(&pool[cur * HC + c], acc);
        if (c == 0) atomicAdd(&cnt[cur], ccount);
    }
}

// ================= final linear: [64,128]@[128,2] + blin =================
__global__ void final_kernel(
    const float* __restrict__ pool, const float* __restrict__ cnt,
    const float* __restrict__ Wlin, const float* __restrict__ blin,
    float* __restrict__ outp)
{
    int t = threadIdx.x;               // 128 threads
    int b = t >> 1, oc = t & 1;
    float inv = 1.f / fmaxf(cnt[b], 1.f);
    float s = blin[oc];
    for (int c = 0; c < HC; ++c)
        s += pool[b * HC + c] * inv * Wlin[c * 2 + oc];
    outp[b * 2 + oc] = s;
}

// ================= workspace layout =================
// floats
static constexpr size_t OFF_OUT   = 0;                        // [N*HC]
static constexpr size_t OFF_AS    = OFF_OUT + (size_t)NN*HC;  // [N*2]
static constexpr size_t OFF_AD    = OFF_AS  + (size_t)NN*HH;
static constexpr size_t OFF_ST1   = OFF_AD  + (size_t)NN*HH;  // zero from here: [2*64*128]
static constexpr size_t OFF_ST2   = OFF_ST1 + 2*64*128;
static constexpr size_t OFF_SC1   = OFF_ST2 + 2*64*128;       // [128]
static constexpr size_t OFF_SH1   = OFF_SC1 + 128;
static constexpr size_t OFF_SC2   = OFF_SH1 + 128;
static constexpr size_t OFF_SH2   = OFF_SC2 + 128;
static constexpr size_t OFF_POOL  = OFF_SH2 + 128;            // [B*HC]
static constexpr size_t OFF_CNT   = OFF_POOL+ (size_t)BB*HC;  // [B]
static constexpr size_t OFF_ZEND  = OFF_CNT + BB;             // end of zeroed float region
// ints (after float region) — deg FIRST so one memset covers floats+deg
static constexpr size_t IOFF_DEG  = 0;                        // [N]  (zeroed)
static constexpr size_t IOFF_ROWP = IOFF_DEG  + NN;           // [N+1]
static constexpr size_t IOFF_CUR  = IOFF_ROWP + NN + 1;       // [N]
static constexpr size_t IOFF_ESRC = IOFF_CUR  + NN;           // [ETOT]
static constexpr size_t IOFF_HB   = (IOFF_ESRC + ETOT + 3) & ~(size_t)3;  // [N*64] uints
static constexpr size_t IOFF_WF1  = IOFF_HB + (size_t)NN*64;  // [512*64] ints
static constexpr size_t IOFF_WF2  = IOFF_WF1 + (size_t)IN_C*64; // [128*64] ints
static constexpr size_t IOFF_END  = IOFF_WF2 + (size_t)HC*64;

extern "C" void kernel_launch(void* const* d_in, const int* in_sizes, int n_in,
                              void* d_out, int out_size, void* d_ws, size_t ws_size,
                              hipStream_t stream)
{
    const float* x       = (const float*)d_in[0];
    const int*   ei      = (const int*)  d_in[1];
    const int*   batch   = (const int*)  d_in[2];
    const float* W1      = (const float*)d_in[3];
    const float* atts1   = (const float*)d_in[4];
    const float* attd1   = (const float*)d_in[5];
    const float* gamma1  = (const float*)d_in[7];
    const float* beta1   = (const float*)d_in[8];
    const float* W2      = (const float*)d_in[9];
    const float* atts2   = (const float*)d_in[10];
    const float* attd2   = (const float*)d_in[11];
    const float* gamma2  = (const float*)d_in[13];
    const float* beta2   = (const float*)d_in[14];
    const float* Wlin    = (const float*)d_in[15];
    const float* blin    = (const float*)d_in[16];
    float* outp = (float*)d_out;

    float* ws    = (float*)d_ws;
    float* out   = ws + OFF_OUT;
    float* as_   = ws + OFF_AS;
    float* ad_   = ws + OFF_AD;
    float* st1   = ws + OFF_ST1;
    float* st2   = ws + OFF_ST2;
    float* sc1   = ws + OFF_SC1;
    float* sh1   = ws + OFF_SH1;
    float* sc2   = ws + OFF_SC2;
    float* sh2   = ws + OFF_SH2;
    float* pool  = ws + OFF_POOL;
    float* cnt   = ws + OFF_CNT;

    int* iws  = (int*)(ws + OFF_ZEND);
    int* deg  = iws + IOFF_DEG;
    int* rowp = iws + IOFF_ROWP;
    int* curp = iws + IOFF_CUR;
    int* esrc = iws + IOFF_ESRC;
    unsigned* hb = (unsigned*)(iws + IOFF_HB);
    unsigned short* Wf1 = (unsigned short*)(iws + IOFF_WF1);
    unsigned short* Wf2 = (unsigned short*)(iws + IOFF_WF2);

    const int BIN_BLK   = NXCD * NSLOT;          // 8 * 416 = 3328
    const int GEMM_BLK  = (NN + 63) / 64;        // 782: 64 rows x 128 cols
    const int WAVE_BLK  = (NN + 3) / 4;          // 1 wave per node, 4 waves/block
    const int POOL_BLK  = (NN + 63) / 64;        // 782: 64 rows/block
    const int WFRG_BLK  = (IN_C * 16 + HC * 16 + 255) / 256;  // 40

    // single memset: bn-stats/sc-sh/pool/cnt float region + deg (contiguous)
    hipMemsetAsync(st1, 0, (OFF_ZEND - OFF_ST1) * sizeof(float) + NN * sizeof(int), stream);

    // ----- weight fragment packs + CSR build (shared by both layers) -----
    wfrag_kernel<<<WFRG_BLK, 256, 0, stream>>>(W1, Wf1, W2, Wf2);
    deg_kernel<<<BIN_BLK, 256, 0, stream>>>(ei, deg);
    scan_kernel<<<1, 256, 0, stream>>>(deg, rowp, curp);
    scatter_kernel<<<BIN_BLK, 256, 0, stream>>>(ei, curp, esrc);

    // ----- layer 1 (GEMM + fused alpha + bf16 pack; agg + fused BN stats) -----
    mfma_gemm_kernel<IN_C, false><<<GEMM_BLK, 256, 0, stream>>>(
        x, Wf1, atts1, attd1, hb, as_, ad_, nullptr, nullptr);
    gat_agg_kernel<<<WAVE_BLK, 256, 0, stream>>>(rowp, esrc, as_, ad_, hb, out, st1);
    bn_params_kernel<<<1, 128, 0, stream>>>(st1, gamma1, beta1, sc1, sh1);

    // ----- layer 2 (BN1-affine+ReLU fused into GEMM2 A-load) -----
    mfma_gemm_kernel<HC, true><<<GEMM_BLK, 256, 0, stream>>>(
        out, Wf2, atts2, attd2, hb, as_, ad_, sc1, sh1);
    gat_agg_kernel<<<WAVE_BLK, 256, 0, stream>>>(rowp, esrc, as_, ad_, hb, out, st2);
    bn_params_kernel<<<1, 128, 0, stream>>>(st2, gamma2, beta2, sc2, sh2);

    // ----- pool + final linear -----
    pool_kernel<<<POOL_BLK, 256, 0, stream>>>(out, sc2, sh2, batch, pool, cnt);
    final_kernel<<<1, 128, 0, stream>>>(pool, cnt, Wlin, blin, outp);
}

// Round 7
// 435.908 us; speedup vs baseline: 1.2335x; 1.2335x over previous
//
#include <hip/hip_runtime.h>
#include <hip/hip_bf16.h>
#include <cstdint>
#include <cstddef>

// Problem constants (match reference)
#define NN      50000
#define IN_C    512
#define EE      800000
#define ETOT    850000      // E + N self-loops
#define HH      2
#define CC      64
#define HC      128
#define BB      64
#define OUTC    2
#define NEG_SLOPE 0.2f
#define BN_EPS  1e-5f

#define NBLK_SCAN ((NN + 255) / 256)   // 196

// XCD binning for CSR build: 8 dst ranges, blockIdx%8 -> XCD (round-robin dispatch)
#define NXCD     8
#define NPX      ((NN + NXCD - 1) / NXCD)        // 6250 nodes per bin
#define EDGES_PER_SLOT 2048
#define NSLOT    ((ETOT + EDGES_PER_SLOT - 1) / EDGES_PER_SLOT)  // 416

typedef __bf16 bf16x8 __attribute__((ext_vector_type(8)));
typedef float  f32x4  __attribute__((ext_vector_type(4)));

__device__ __forceinline__ unsigned f2bf(float f) {
    __bf16 b = (__bf16)f;                      // RNE convert
    return (unsigned)__builtin_bit_cast(unsigned short, b);
}

// async global->LDS, 16B per lane; LDS dest is wave-uniform base + lane*16
__device__ __forceinline__ void gload_lds16(const float* g, float* l) {
    __builtin_amdgcn_global_load_lds(
        (const __attribute__((address_space(1))) unsigned*)g,
        (__attribute__((address_space(3))) unsigned*)l,
        16, 0, 0);
}

// ================= CSR build (XCD-binned: each XCD owns a dst range; atomics and
// esrc writes stay in one L2 — no cross-XCD line ping-pong / write amplification) ==========
__global__ __launch_bounds__(256) void deg_kernel(const int* __restrict__ ei, int* __restrict__ deg)
{
    const int xcd  = blockIdx.x & (NXCD - 1);
    const int slot = blockIdx.x >> 3;
    const int lo = xcd * NPX, hi = lo + NPX;
    const int base = slot * EDGES_PER_SLOT;
#pragma unroll
    for (int it = 0; it < EDGES_PER_SLOT / 256; ++it) {
        int e = base + it * 256 + threadIdx.x;
        if (e < ETOT) {
            int d = (e < EE) ? ei[EE + e] : (e - EE);
            if (d >= lo && d < hi) atomicAdd(&deg[d], 1);
        }
    }
}

// --- hierarchical scan (3 tiny kernels; R6's single-block fusion was 15x slower) ---
__global__ __launch_bounds__(256) void bsum_kernel(const int* __restrict__ deg, int* __restrict__ bsum)
{
    int i = blockIdx.x * 256 + threadIdx.x;
    int v = (i < NN) ? deg[i] : 0;
    int lane = threadIdx.x & 63, wv = threadIdx.x >> 6;
#pragma unroll
    for (int o = 32; o > 0; o >>= 1) v += __shfl_down(v, o);
    __shared__ int ws[4];
    if (lane == 0) ws[wv] = v;
    __syncthreads();
    if (threadIdx.x == 0) bsum[blockIdx.x] = ws[0] + ws[1] + ws[2] + ws[3];
}

__global__ __launch_bounds__(256) void bscan_kernel(
    const int* __restrict__ bsum, int* __restrict__ bofs, int* __restrict__ rowp)
{
    int t = threadIdx.x;
    int lane = t & 63, wv = t >> 6;
    int v = (t < NBLK_SCAN) ? bsum[t] : 0;
    int x = v;
#pragma unroll
    for (int o = 1; o < 64; o <<= 1) {
        int y = __shfl_up(x, o);
        if (lane >= o) x += y;
    }
    __shared__ int ws[4];
    if (lane == 63) ws[wv] = x;
    __syncthreads();
    int wo = 0;
#pragma unroll
    for (int w = 0; w < 4; ++w) if (w < wv) wo += ws[w];
    if (t < NBLK_SCAN) bofs[t] = x + wo - v;     // exclusive
    if (t == 0) rowp[NN] = ETOT;
}

__global__ __launch_bounds__(256) void bapply_kernel(
    const int* __restrict__ deg, const int* __restrict__ bofs,
    int* __restrict__ rowp, int* __restrict__ cur)
{
    int i = blockIdx.x * 256 + threadIdx.x;
    int v = (i < NN) ? deg[i] : 0;
    int lane = threadIdx.x & 63, wv = threadIdx.x >> 6;
    int x = v;
#pragma unroll
    for (int o = 1; o < 64; o <<= 1) {
        int y = __shfl_up(x, o);
        if (lane >= o) x += y;
    }
    __shared__ int ws[4];
    if (lane == 63) ws[wv] = x;
    __syncthreads();
    int wo = 0;
#pragma unroll
    for (int w = 0; w < 4; ++w) if (w < wv) wo += ws[w];
    if (i < NN) {
        int r = bofs[blockIdx.x] + x + wo - v;   // exclusive global
        rowp[i] = r; cur[i] = r;
    }
}

__global__ __launch_bounds__(256) void scatter_kernel(
    const int* __restrict__ ei, int* __restrict__ cur, int* __restrict__ esrc)
{
    const int xcd  = blockIdx.x & (NXCD - 1);
    const int slot = blockIdx.x >> 3;
    const int lo = xcd * NPX, hi = lo + NPX;
    const int base = slot * EDGES_PER_SLOT;
#pragma unroll
    for (int it = 0; it < EDGES_PER_SLOT / 256; ++it) {
        int e = base + it * 256 + threadIdx.x;
        if (e < ETOT) {
            int s, d;
            if (e < EE) { s = ei[e]; d = ei[EE + e]; }
            else        { s = e - EE; d = s; }
            if (d >= lo && d < hi) {
                int pos = atomicAdd(&cur[d], 1);
                esrc[pos] = s;
            }
        }
    }
}

// ================= W -> bf16 MFMA fragment order (both weights in one launch) ========
__global__ __launch_bounds__(256) void wfrag_kernel(
    const float* __restrict__ W1, unsigned short* __restrict__ Wf1,
    const float* __restrict__ W2, unsigned short* __restrict__ Wf2)
{
    int t = blockIdx.x * 256 + threadIdx.x;
    const float* W; unsigned short* Wf;
    if (t < IN_C * 16) { W = W1; Wf = Wf1; }
    else {
        t -= IN_C * 16;
        if (t >= HC * 16) return;
        W = W2; Wf = Wf2;
    }
    int lane = t & 63, frag = t >> 6;
    int kblk = frag >> 3, nt = frag & 7;
    int quad = lane >> 4, ln = lane & 15;
    int kbase = kblk * 32 + quad * 8;
    int n = nt * 16 + ln;
    unsigned short u[8];
#pragma unroll
    for (int j = 0; j < 8; ++j)
        u[j] = (unsigned short)f2bf(W[(size_t)(kbase + j) * HC + n]);
    ushort4 a; a.x = u[0]; a.y = u[1]; a.z = u[2]; a.w = u[3];
    ushort4 b; b.x = u[4]; b.y = u[5]; b.z = u[6]; b.w = u[7];
    *(ushort4*)(Wf + (size_t)t * 8)     = a;
    *(ushort4*)(Wf + (size_t)t * 8 + 4) = b;
}

// ================= LDS-staged MFMA GEMM, BK=64 per barrier (R4-measured form) =========
// Block = 64 rows x 128 cols, 4 waves. A staged via global_load_lds into a 2 x 16 KB
// double buffer, TWO 32-wide K-substeps per barrier. LDS sub-tile [64][32] XOR-swizzled
// via pre-swizzled global source (rule 21). B streamed from L2 in regs, double-buffered.
template<int K, bool AFFINE>
__global__ __launch_bounds__(256) void mfma_gemm_kernel(
    const float* __restrict__ A, const unsigned short* __restrict__ Wf,
    const float* __restrict__ atts, const float* __restrict__ attd,
    unsigned* __restrict__ hb, float* __restrict__ as_, float* __restrict__ ad_,
    const float* __restrict__ sc, const float* __restrict__ sh)
{
    constexpr int NSTEP = K >> 5;                   // 32-wide substeps
    __shared__ __align__(16) float Abuf[2][64 * 64]; // 2 x 16 KB

    const int tid  = threadIdx.x;
    const int wave = tid >> 6, lane = tid & 63;
    const int quad = lane >> 4, ln = lane & 15;
    const int m0 = blockIdx.x * 64;

    // staging geometry: thread t covers 16B slot (row t>>3, slot t&7), rows +0/+32
    const int srow = tid >> 3;
    const int g    = (tid & 7) ^ (srow & 7);        // swizzled source slot
    int grow0 = m0 + srow;      if (grow0 > NN - 1) grow0 = NN - 1;
    int grow1 = m0 + srow + 32; if (grow1 > NN - 1) grow1 = NN - 1;
    const float* gsrc0 = A + (size_t)grow0 * K + g * 4;
    const float* gsrc1 = A + (size_t)grow1 * K + g * 4;

    // fragment-read geometry
    const int rr = wave * 16 + ln;
    const int base_f = rr * 32;
    const int sA = (((quad * 2)     ^ (rr & 7)) * 4);
    const int sB = (((quad * 2 + 1) ^ (rr & 7)) * 4);

    const unsigned short* wbase = Wf + lane * 8;

    f32x4 acc[8];
#pragma unroll
    for (int nt = 0; nt < 8; ++nt) acc[nt] = (f32x4){0.f, 0.f, 0.f, 0.f};

    // prologue: stage substeps 0,1 into buf0; load B frags for ks=0
    gload_lds16(gsrc0,      &Abuf[0][wave * 256]);
    gload_lds16(gsrc1,      &Abuf[0][1024 + wave * 256]);
    gload_lds16(gsrc0 + 32, &Abuf[0][2048 + wave * 256]);
    gload_lds16(gsrc1 + 32, &Abuf[0][3072 + wave * 256]);
    bf16x8 bfr[2][8];
#pragma unroll
    for (int nt = 0; nt < 8; ++nt) bfr[0][nt] = *(const bf16x8*)(wbase + nt * 512);

#pragma unroll
    for (int ks = 0; ks < NSTEP; ++ks) {
        const int sub  = ks & 1;             // substep within BK=64
        const int cbuf = (ks >> 1) & 1;      // LDS buffer
        const int bsel = ks & 1;             // rolling B-frag buffer
        if (sub == 0) {
            // barrier drains vmcnt(0): stage(kb) loads issued a full BK-iter ago are in
            __syncthreads();
            if (ks + 2 < NSTEP) {
                const float* n0 = gsrc0 + (size_t)(ks + 2) * 32;
                const float* n1 = gsrc1 + (size_t)(ks + 2) * 32;
                float* db = &Abuf[cbuf ^ 1][wave * 256];
                gload_lds16(n0,      db);
                gload_lds16(n1,      db + 1024);
                gload_lds16(n0 + 32, db + 2048);
                gload_lds16(n1 + 32, db + 3072);
            }
        }

        const float* fb_base = &Abuf[cbuf][sub * 2048 + base_f];
        float4 fa = *(const float4*)(fb_base + sA);
        float4 fb = *(const float4*)(fb_base + sB);
        float va[8] = {fa.x, fa.y, fa.z, fa.w, fb.x, fb.y, fb.z, fb.w};
        if (AFFINE) {
            const int kk = ks * 32 + quad * 8;
            const float4 s0 = *(const float4*)(sc + kk), s1 = *(const float4*)(sc + kk + 4);
            const float4 h0 = *(const float4*)(sh + kk), h1 = *(const float4*)(sh + kk + 4);
            va[0] = fmaxf(fmaf(s0.x, va[0], h0.x), 0.f);
            va[1] = fmaxf(fmaf(s0.y, va[1], h0.y), 0.f);
            va[2] = fmaxf(fmaf(s0.z, va[2], h0.z), 0.f);
            va[3] = fmaxf(fmaf(s0.w, va[3], h0.w), 0.f);
            va[4] = fmaxf(fmaf(s1.x, va[4], h1.x), 0.f);
            va[5] = fmaxf(fmaf(s1.y, va[5], h1.y), 0.f);
            va[6] = fmaxf(fmaf(s1.z, va[6], h1.z), 0.f);
            va[7] = fmaxf(fmaf(s1.w, va[7], h1.w), 0.f);
        }
        union { bf16x8 v; unsigned short u[8]; } af;
#pragma unroll
        for (int j = 0; j < 8; ++j) af.u[j] = (unsigned short)f2bf(va[j]);

        // prefetch next substep's B-frags (L2-hot; in flight across this step's MFMAs)
        if (ks + 1 < NSTEP) {
            const unsigned short* wfp = wbase + (size_t)(ks + 1) * 4096;
#pragma unroll
            for (int nt = 0; nt < 8; ++nt)
                bfr[bsel ^ 1][nt] = *(const bf16x8*)(wfp + nt * 512);
        }

#pragma unroll
        for (int nt = 0; nt < 8; ++nt)
            acc[nt] = __builtin_amdgcn_mfma_f32_16x16x32_bf16(af.v, bfr[bsel][nt], acc[nt], 0, 0, 0);
    }

    // epilogue: pack bf16 pairs + fused attention logits; C/D layout col=ln, row=quad*4+r
    float wsv[8], wdv[8];
#pragma unroll
    for (int nt = 0; nt < 8; ++nt) { wsv[nt] = atts[nt * 16 + ln]; wdv[nt] = attd[nt * 16 + ln]; }

    const int mbase = m0 + wave * 16 + quad * 4;
#pragma unroll
    for (int r = 0; r < 4; ++r) {
        int m = mbase + r;
        bool ok = (m < NN);
        float ps0 = 0.f, ps1 = 0.f, pd0 = 0.f, pd1 = 0.f;
#pragma unroll
        for (int nt = 0; nt < 8; ++nt) {
            float v = acc[nt][r];
            if (nt < 4) { ps0 = fmaf(v, wsv[nt], ps0); pd0 = fmaf(v, wdv[nt], pd0); }
            else        { ps1 = fmaf(v, wsv[nt], ps1); pd1 = fmaf(v, wdv[nt], pd1); }
        }
#pragma unroll
        for (int nt = 0; nt < 4; ++nt) {
            unsigned pk = f2bf(acc[nt][r]) | (f2bf(acc[nt + 4][r]) << 16);
            if (ok) hb[(size_t)m * 64 + nt * 16 + ln] = pk;
        }
#pragma unroll
        for (int o = 8; o > 0; o >>= 1) {
            ps0 += __shfl_down(ps0, o); ps1 += __shfl_down(ps1, o);
            pd0 += __shfl_down(pd0, o); pd1 += __shfl_down(pd1, o);
        }
        if (ok && ln == 0) {
            *(float2*)&as_[m * 2] = make_float2(ps0, ps1);
            *(float2*)&ad_[m * 2] = make_float2(pd0, pd1);
        }
    }
}

// ================= fused segment-softmax + aggregate + BN-stats partials =============
// One wave per dst node. Broadcast via wave-private LDS float4 slots: chunk phase
// writes (src, p0, p1) per lane; the serial loop does ONE uniform ds_read_b128 per
// edge (broadcasts to all lanes, conflict-free) instead of 3 ds_bpermute shfls —
// cuts LDS-pipe ops per edge 3 -> ~1. Same-wave LDS write->read is in-order, no barrier.
__global__ __launch_bounds__(256) void gat_agg_kernel(
    const int* __restrict__ rowp, const int* __restrict__ esrc,
    const float* __restrict__ as_, const float* __restrict__ ad_,
    const unsigned* __restrict__ hb, float* __restrict__ out,
    float* __restrict__ stats)
{
    const int tid  = threadIdx.x;
    const int node = (blockIdx.x * 256 + tid) >> 6;
    const int wave = tid >> 6;
    const int lane = tid & 63;
    int beg = rowp[node], end = rowp[node + 1];
    float2 adv = *(const float2*)&ad_[node * 2];

    __shared__ __align__(16) float4 stg[4][64];
    float4* sw = stg[wave];

    float l0 = 0.f, l1 = 0.f, a0 = 0.f, a1 = 0.f;

    for (int j0 = beg; j0 < end; j0 += 64) {
        int nj = min(64, end - j0);
        float p0l = 0.f, p1l = 0.f;
        if (j0 + lane < end) {
            int sl = esrc[j0 + lane];
            float2 t = *(const float2*)&as_[sl * 2];
            float e0 = t.x + adv.x; e0 = fmaxf(e0, NEG_SLOPE * e0);
            float e1 = t.y + adv.y; e1 = fmaxf(e1, NEG_SLOPE * e1);
            p0l = __expf(e0); p1l = __expf(e1);
            sw[lane] = make_float4(__int_as_float(sl), p0l, p1l, 0.f);
        }
        l0 += p0l; l1 += p1l;          // per-lane partial denominator

        int j = 0;
        for (; j + 8 <= nj; j += 8) {
            float4 t0 = sw[j],     t1 = sw[j + 1], t2 = sw[j + 2], t3 = sw[j + 3];
            float4 t4 = sw[j + 4], t5 = sw[j + 5], t6 = sw[j + 6], t7 = sw[j + 7];
            unsigned u0 = hb[(size_t)__float_as_int(t0.x) * 64 + lane];
            unsigned u1 = hb[(size_t)__float_as_int(t1.x) * 64 + lane];
            unsigned u2 = hb[(size_t)__float_as_int(t2.x) * 64 + lane];
            unsigned u3 = hb[(size_t)__float_as_int(t3.x) * 64 + lane];
            unsigned u4 = hb[(size_t)__float_as_int(t4.x) * 64 + lane];
            unsigned u5 = hb[(size_t)__float_as_int(t5.x) * 64 + lane];
            unsigned u6 = hb[(size_t)__float_as_int(t6.x) * 64 + lane];
            unsigned u7 = hb[(size_t)__float_as_int(t7.x) * 64 + lane];
            a0 = fmaf(t0.y, __uint_as_float(u0 << 16), a0);
            a1 = fmaf(t0.z, __uint_as_float(u0 & 0xffff0000u), a1);
            a0 = fmaf(t1.y, __uint_as_float(u1 << 16), a0);
            a1 = fmaf(t1.z, __uint_as_float(u1 & 0xffff0000u), a1);
            a0 = fmaf(t2.y, __uint_as_float(u2 << 16), a0);
            a1 = fmaf(t2.z, __uint_as_float(u2 & 0xffff0000u), a1);
            a0 = fmaf(t3.y, __uint_as_float(u3 << 16), a0);
            a1 = fmaf(t3.z, __uint_as_float(u3 & 0xffff0000u), a1);
            a0 = fmaf(t4.y, __uint_as_float(u4 << 16), a0);
            a1 = fmaf(t4.z, __uint_as_float(u4 & 0xffff0000u), a1);
            a0 = fmaf(t5.y, __uint_as_float(u5 << 16), a0);
            a1 = fmaf(t5.z, __uint_as_float(u5 & 0xffff0000u), a1);
            a0 = fmaf(t6.y, __uint_as_float(u6 << 16), a0);
            a1 = fmaf(t6.z, __uint_as_float(u6 & 0xffff0000u), a1);
            a0 = fmaf(t7.y, __uint_as_float(u7 << 16), a0);
            a1 = fmaf(t7.z, __uint_as_float(u7 & 0xffff0000u), a1);
        }
        for (; j < nj; ++j) {
            float4 t = sw[j];
            unsigned u = hb[(size_t)__float_as_int(t.x) * 64 + lane];
            a0 = fmaf(t.y, __uint_as_float(u << 16), a0);
            a1 = fmaf(t.z, __uint_as_float(u & 0xffff0000u), a1);
        }
    }

#pragma unroll
    for (int o = 1; o < 64; o <<= 1) {
        l0 += __shfl_xor(l0, o); l1 += __shfl_xor(l1, o);
    }
    float v0 = a0 / l0;
    float v1 = a1 / l1;
    out[(size_t)node * HC + lane]      = v0;
    out[(size_t)node * HC + 64 + lane] = v1;

    // ---- fused BN-stats partials ----
    __shared__ float red[4][256];
    red[wave][lane]      = v0;
    red[wave][64 + lane] = v1;
    __syncthreads();
    if (tid < 128) {
        float s = 0.f, q = 0.f;
#pragma unroll
        for (int w = 0; w < 4; ++w) {
            float v = red[w][tid];
            s += v; q = fmaf(v, v, q);
        }
        int slot = blockIdx.x & 63;
        atomicAdd(&stats[slot * 128 + tid], s);
        atomicAdd(&stats[64 * 128 + slot * 128 + tid], q);
    }
}

// ================= BN params: reduce 64 stat slices =================
__global__ void bn_params_kernel(
    const float* __restrict__ stats, const float* __restrict__ gamma,
    const float* __restrict__ beta, float* __restrict__ sc, float* __restrict__ sh)
{
    int c = threadIdx.x;                  // 128 threads
    float su = 0.f, sq = 0.f;
#pragma unroll
    for (int k = 0; k < 64; ++k) {
        su += stats[k * 128 + c];
        sq += stats[64 * 128 + k * 128 + c];
    }
    const float inv_n = 1.0f / (float)NN;
    float mu = su * inv_n;
    float var = sq * inv_n - mu * mu;
    float rs = rsqrtf(var + BN_EPS);
    float s = gamma[c] * rs;
    sc[c] = s;
    sh[c] = beta[c] - mu * s;
}

// ================= pool: 64 rows/block (782 blocks), flush-on-graph-change =================
__global__ __launch_bounds__(256) void pool_kernel(
    const float* __restrict__ x, const float* __restrict__ sc,
    const float* __restrict__ sh, const int* __restrict__ batch,
    float* __restrict__ pool, float* __restrict__ cnt)
{
    int c = threadIdx.x & 127;
    int half = threadIdx.x >> 7;
    int r0 = blockIdx.x * 64;
    int rend = min(r0 + 64, NN);
    float s = sc[c], b = sh[c];
    int cur = -1; float acc = 0.f, ccount = 0.f;
    for (int r = r0 + half; r < rend; r += 2) {
        int g = batch[r];
        if (g != cur) {
            if (cur >= 0) {
                atomicAdd(&pool[cur * HC + c], acc);
                if (c == 0) atomicAdd(&cnt[cur], ccount);
            }
            cur = g; acc = 0.f; ccount = 0.f;
        }
        float v = x[(size_t)r * HC + c];
        acc += fmaxf(fmaf(s, v, b), 0.f);
        ccount += 1.f;
    }
    if (cur >= 0) {
        atomicAdd(&pool[cur * HC + c], acc);
        if (c == 0) atomicAdd(&cnt[cur], ccount);
    }
}

// ================= final linear: [64,128]@[128,2] + blin =================
__global__ void final_kernel(
    const float* __restrict__ pool, const float* __restrict__ cnt,
    const float* __restrict__ Wlin, const float* __restrict__ blin,
    float* __restrict__ outp)
{
    int t = threadIdx.x;               // 128 threads
    int b = t >> 1, oc = t & 1;
    float inv = 1.f / fmaxf(cnt[b], 1.f);
    float s = blin[oc];
    for (int c = 0; c < HC; ++c)
        s += pool[b * HC + c] * inv * Wlin[c * 2 + oc];
    outp[b * 2 + oc] = s;
}

// ================= workspace layout =================
// floats
static constexpr size_t OFF_OUT   = 0;                        // [N*HC]
static constexpr size_t OFF_AS    = OFF_OUT + (size_t)NN*HC;  // [N*2]
static constexpr size_t OFF_AD    = OFF_AS  + (size_t)NN*HH;
static constexpr size_t OFF_ST1   = OFF_AD  + (size_t)NN*HH;  // zero from here: [2*64*128]
static constexpr size_t OFF_ST2   = OFF_ST1 + 2*64*128;
static constexpr size_t OFF_SC1   = OFF_ST2 + 2*64*128;       // [128]
static constexpr size_t OFF_SH1   = OFF_SC1 + 128;
static constexpr size_t OFF_SC2   = OFF_SH1 + 128;
static constexpr size_t OFF_SH2   = OFF_SC2 + 128;
static constexpr size_t OFF_POOL  = OFF_SH2 + 128;            // [B*HC]
static constexpr size_t OFF_CNT   = OFF_POOL+ (size_t)BB*HC;  // [B]
static constexpr size_t OFF_ZEND  = OFF_CNT + BB;             // end of zeroed float region
// ints (after float region) — deg FIRST so one memset covers floats+deg
static constexpr size_t IOFF_DEG  = 0;                        // [N]  (zeroed)
static constexpr size_t IOFF_ROWP = IOFF_DEG  + NN;           // [N+1]
static constexpr size_t IOFF_CUR  = IOFF_ROWP + NN + 1;       // [N]
static constexpr size_t IOFF_BSUM = IOFF_CUR  + NN;           // [NBLK_SCAN]
static constexpr size_t IOFF_BOFS = IOFF_BSUM + NBLK_SCAN;    // [NBLK_SCAN]
static constexpr size_t IOFF_ESRC = IOFF_BOFS + NBLK_SCAN;    // [ETOT]
static constexpr size_t IOFF_HB   = (IOFF_ESRC + ETOT + 3) & ~(size_t)3;  // [N*64] uints
static constexpr size_t IOFF_WF1  = IOFF_HB + (size_t)NN*64;  // [512*64] ints
static constexpr size_t IOFF_WF2  = IOFF_WF1 + (size_t)IN_C*64; // [128*64] ints
static constexpr size_t IOFF_END  = IOFF_WF2 + (size_t)HC*64;

extern "C" void kernel_launch(void* const* d_in, const int* in_sizes, int n_in,
                              void* d_out, int out_size, void* d_ws, size_t ws_size,
                              hipStream_t stream)
{
    const float* x       = (const float*)d_in[0];
    const int*   ei      = (const int*)  d_in[1];
    const int*   batch   = (const int*)  d_in[2];
    const float* W1      = (const float*)d_in[3];
    const float* atts1   = (const float*)d_in[4];
    const float* attd1   = (const float*)d_in[5];
    const float* gamma1  = (const float*)d_in[7];
    const float* beta1   = (const float*)d_in[8];
    const float* W2      = (const float*)d_in[9];
    const float* atts2   = (const float*)d_in[10];
    const float* attd2   = (const float*)d_in[11];
    const float* gamma2  = (const float*)d_in[13];
    const float* beta2   = (const float*)d_in[14];
    const float* Wlin    = (const float*)d_in[15];
    const float* blin    = (const float*)d_in[16];
    float* outp = (float*)d_out;

    float* ws    = (float*)d_ws;
    float* out   = ws + OFF_OUT;
    float* as_   = ws + OFF_AS;
    float* ad_   = ws + OFF_AD;
    float* st1   = ws + OFF_ST1;
    float* st2   = ws + OFF_ST2;
    float* sc1   = ws + OFF_SC1;
    float* sh1   = ws + OFF_SH1;
    float* sc2   = ws + OFF_SC2;
    float* sh2   = ws + OFF_SH2;
    float* pool  = ws + OFF_POOL;
    float* cnt   = ws + OFF_CNT;

    int* iws  = (int*)(ws + OFF_ZEND);
    int* deg  = iws + IOFF_DEG;
    int* rowp = iws + IOFF_ROWP;
    int* curp = iws + IOFF_CUR;
    int* bsum = iws + IOFF_BSUM;
    int* bofs = iws + IOFF_BOFS;
    int* esrc = iws + IOFF_ESRC;
    unsigned* hb = (unsigned*)(iws + IOFF_HB);
    unsigned short* Wf1 = (unsigned short*)(iws + IOFF_WF1);
    unsigned short* Wf2 = (unsigned short*)(iws + IOFF_WF2);

    const int BIN_BLK   = NXCD * NSLOT;          // 8 * 416 = 3328
    const int GEMM_BLK  = (NN + 63) / 64;        // 782: 64 rows x 128 cols
    const int WAVE_BLK  = (NN + 3) / 4;          // 1 wave per node, 4 waves/block
    const int POOL_BLK  = (NN + 63) / 64;        // 782: 64 rows/block
    const int WFRG_BLK  = (IN_C * 16 + HC * 16 + 255) / 256;  // 40

    // single memset: bn-stats/sc-sh/pool/cnt float region + deg (contiguous)
    hipMemsetAsync(st1, 0, (OFF_ZEND - OFF_ST1) * sizeof(float) + NN * sizeof(int), stream);

    // ----- weight fragment packs + CSR build (shared by both layers) -----
    wfrag_kernel<<<WFRG_BLK, 256, 0, stream>>>(W1, Wf1, W2, Wf2);
    deg_kernel<<<BIN_BLK, 256, 0, stream>>>(ei, deg);
    bsum_kernel<<<NBLK_SCAN, 256, 0, stream>>>(deg, bsum);
    bscan_kernel<<<1, 256, 0, stream>>>(bsum, bofs, rowp);
    bapply_kernel<<<NBLK_SCAN, 256, 0, stream>>>(deg, bofs, rowp, curp);
    scatter_kernel<<<BIN_BLK, 256, 0, stream>>>(ei, curp, esrc);

    // ----- layer 1 (GEMM + fused alpha + bf16 pack; agg + fused BN stats) -----
    mfma_gemm_kernel<IN_C, false><<<GEMM_BLK, 256, 0, stream>>>(
        x, Wf1, atts1, attd1, hb, as_, ad_, nullptr, nullptr);
    gat_agg_kernel<<<WAVE_BLK, 256, 0, stream>>>(rowp, esrc, as_, ad_, hb, out, st1);
    bn_params_kernel<<<1, 128, 0, stream>>>(st1, gamma1, beta1, sc1, sh1);

    // ----- layer 2 (BN1-affine+ReLU fused into GEMM2 A-load) -----
    mfma_gemm_kernel<HC, true><<<GEMM_BLK, 256, 0, stream>>>(
        out, Wf2, atts2, attd2, hb, as_, ad_, sc1, sh1);
    gat_agg_kernel<<<WAVE_BLK, 256, 0, stream>>>(rowp, esrc, as_, ad_, hb, out, st2);
    bn_params_kernel<<<1, 128, 0, stream>>>(st2, gamma2, beta2, sc2, sh2);

    // ----- pool + final linear -----
    pool_kernel<<<POOL_BLK, 256, 0, stream>>>(out, sc2, sh2, batch, pool, cnt);
    final_kernel<<<1, 128, 0, stream>>>(pool, cnt, Wlin, blin, outp);
}

// Round 8
// 417.513 us; speedup vs baseline: 1.2878x; 1.0441x over previous
//
#include <hip/hip_runtime.h>
#include <hip/hip_bf16.h>
#include <cstdint>
#include <cstddef>

// Problem constants (match reference)
#define NN      50000
#define IN_C    512
#define EE      800000
#define ETOT    850000      // E + N self-loops
#define HH      2
#define CC      64
#define HC      128
#define BB      64
#define OUTC    2
#define NEG_SLOPE 0.2f
#define BN_EPS  1e-5f

#define NBLK_SCAN ((NN + 255) / 256)   // 196

// XCD binning for CSR build: 8 dst ranges, blockIdx%8 -> XCD (round-robin dispatch)
#define NXCD     8
#define NPX      ((NN + NXCD - 1) / NXCD)        // 6250 nodes per bin
#define EDGES_PER_SLOT 2048
#define NSLOT    ((ETOT + EDGES_PER_SLOT - 1) / EDGES_PER_SLOT)  // 416

typedef __bf16 bf16x8 __attribute__((ext_vector_type(8)));
typedef float  f32x4  __attribute__((ext_vector_type(4)));

__device__ __forceinline__ unsigned f2bf(float f) {
    __bf16 b = (__bf16)f;                      // RNE convert
    return (unsigned)__builtin_bit_cast(unsigned short, b);
}

// async global->LDS, 16B per lane; LDS dest is wave-uniform base + lane*16
__device__ __forceinline__ void gload_lds16(const float* g, float* l) {
    __builtin_amdgcn_global_load_lds(
        (const __attribute__((address_space(1))) unsigned*)g,
        (__attribute__((address_space(3))) unsigned*)l,
        16, 0, 0);
}

// ================= CSR build (XCD-binned: each XCD owns a dst range; atomics and
// esrc writes stay in one L2 — no cross-XCD line ping-pong / write amplification) ==========
__global__ __launch_bounds__(256) void deg_kernel(const int* __restrict__ ei, int* __restrict__ deg)
{
    const int xcd  = blockIdx.x & (NXCD - 1);
    const int slot = blockIdx.x >> 3;
    const int lo = xcd * NPX, hi = lo + NPX;
    const int base = slot * EDGES_PER_SLOT;
#pragma unroll
    for (int it = 0; it < EDGES_PER_SLOT / 256; ++it) {
        int e = base + it * 256 + threadIdx.x;
        if (e < ETOT) {
            int d = (e < EE) ? ei[EE + e] : (e - EE);
            if (d >= lo && d < hi) atomicAdd(&deg[d], 1);
        }
    }
}

// --- hierarchical scan (3 tiny kernels; R6's single-block fusion was 15x slower) ---
__global__ __launch_bounds__(256) void bsum_kernel(const int* __restrict__ deg, int* __restrict__ bsum)
{
    int i = blockIdx.x * 256 + threadIdx.x;
    int v = (i < NN) ? deg[i] : 0;
    int lane = threadIdx.x & 63, wv = threadIdx.x >> 6;
#pragma unroll
    for (int o = 32; o > 0; o >>= 1) v += __shfl_down(v, o);
    __shared__ int ws[4];
    if (lane == 0) ws[wv] = v;
    __syncthreads();
    if (threadIdx.x == 0) bsum[blockIdx.x] = ws[0] + ws[1] + ws[2] + ws[3];
}

__global__ __launch_bounds__(256) void bscan_kernel(
    const int* __restrict__ bsum, int* __restrict__ bofs, int* __restrict__ rowp)
{
    int t = threadIdx.x;
    int lane = t & 63, wv = t >> 6;
    int v = (t < NBLK_SCAN) ? bsum[t] : 0;
    int x = v;
#pragma unroll
    for (int o = 1; o < 64; o <<= 1) {
        int y = __shfl_up(x, o);
        if (lane >= o) x += y;
    }
    __shared__ int ws[4];
    if (lane == 63) ws[wv] = x;
    __syncthreads();
    int wo = 0;
#pragma unroll
    for (int w = 0; w < 4; ++w) if (w < wv) wo += ws[w];
    if (t < NBLK_SCAN) bofs[t] = x + wo - v;     // exclusive
    if (t == 0) rowp[NN] = ETOT;
}

__global__ __launch_bounds__(256) void bapply_kernel(
    const int* __restrict__ deg, const int* __restrict__ bofs,
    int* __restrict__ rowp, int* __restrict__ cur)
{
    int i = blockIdx.x * 256 + threadIdx.x;
    int v = (i < NN) ? deg[i] : 0;
    int lane = threadIdx.x & 63, wv = threadIdx.x >> 6;
    int x = v;
#pragma unroll
    for (int o = 1; o < 64; o <<= 1) {
        int y = __shfl_up(x, o);
        if (lane >= o) x += y;
    }
    __shared__ int ws[4];
    if (lane == 63) ws[wv] = x;
    __syncthreads();
    int wo = 0;
#pragma unroll
    for (int w = 0; w < 4; ++w) if (w < wv) wo += ws[w];
    if (i < NN) {
        int r = bofs[blockIdx.x] + x + wo - v;   // exclusive global
        rowp[i] = r; cur[i] = r;
    }
}

__global__ __launch_bounds__(256) void scatter_kernel(
    const int* __restrict__ ei, int* __restrict__ cur, int* __restrict__ esrc)
{
    const int xcd  = blockIdx.x & (NXCD - 1);
    const int slot = blockIdx.x >> 3;
    const int lo = xcd * NPX, hi = lo + NPX;
    const int base = slot * EDGES_PER_SLOT;
#pragma unroll
    for (int it = 0; it < EDGES_PER_SLOT / 256; ++it) {
        int e = base + it * 256 + threadIdx.x;
        if (e < ETOT) {
            int s, d;
            if (e < EE) { s = ei[e]; d = ei[EE + e]; }
            else        { s = e - EE; d = s; }
            if (d >= lo && d < hi) {
                int pos = atomicAdd(&cur[d], 1);
                esrc[pos] = s;
            }
        }
    }
}

// ================= W -> bf16 MFMA fragment order (both weights in one launch) ========
__global__ __launch_bounds__(256) void wfrag_kernel(
    const float* __restrict__ W1, unsigned short* __restrict__ Wf1,
    const float* __restrict__ W2, unsigned short* __restrict__ Wf2)
{
    int t = blockIdx.x * 256 + threadIdx.x;
    const float* W; unsigned short* Wf;
    if (t < IN_C * 16) { W = W1; Wf = Wf1; }
    else {
        t -= IN_C * 16;
        if (t >= HC * 16) return;
        W = W2; Wf = Wf2;
    }
    int lane = t & 63, frag = t >> 6;
    int kblk = frag >> 3, nt = frag & 7;
    int quad = lane >> 4, ln = lane & 15;
    int kbase = kblk * 32 + quad * 8;
    int n = nt * 16 + ln;
    unsigned short u[8];
#pragma unroll
    for (int j = 0; j < 8; ++j)
        u[j] = (unsigned short)f2bf(W[(size_t)(kbase + j) * HC + n]);
    ushort4 a; a.x = u[0]; a.y = u[1]; a.z = u[2]; a.w = u[3];
    ushort4 b; b.x = u[4]; b.y = u[5]; b.z = u[6]; b.w = u[7];
    *(ushort4*)(Wf + (size_t)t * 8)     = a;
    *(ushort4*)(Wf + (size_t)t * 8 + 4) = b;
}

// ================= LDS-staged MFMA GEMM, BK=64 per barrier (R4-measured form) =========
// Block = 64 rows x 128 cols, 4 waves. A staged via global_load_lds into a 2 x 16 KB
// double buffer, TWO 32-wide K-substeps per barrier. LDS sub-tile [64][32] XOR-swizzled
// via pre-swizzled global source (rule 21). B streamed from L2 in regs, double-buffered.
template<int K, bool AFFINE>
__global__ __launch_bounds__(256) void mfma_gemm_kernel(
    const float* __restrict__ A, const unsigned short* __restrict__ Wf,
    const float* __restrict__ atts, const float* __restrict__ attd,
    unsigned* __restrict__ hb, float* __restrict__ as_, float* __restrict__ ad_,
    const float* __restrict__ sc, const float* __restrict__ sh)
{
    constexpr int NSTEP = K >> 5;                   // 32-wide substeps
    __shared__ __align__(16) float Abuf[2][64 * 64]; // 2 x 16 KB

    const int tid  = threadIdx.x;
    const int wave = tid >> 6, lane = tid & 63;
    const int quad = lane >> 4, ln = lane & 15;
    const int m0 = blockIdx.x * 64;

    // staging geometry: thread t covers 16B slot (row t>>3, slot t&7), rows +0/+32
    const int srow = tid >> 3;
    const int g    = (tid & 7) ^ (srow & 7);        // swizzled source slot
    int grow0 = m0 + srow;      if (grow0 > NN - 1) grow0 = NN - 1;
    int grow1 = m0 + srow + 32; if (grow1 > NN - 1) grow1 = NN - 1;
    const float* gsrc0 = A + (size_t)grow0 * K + g * 4;
    const float* gsrc1 = A + (size_t)grow1 * K + g * 4;

    // fragment-read geometry
    const int rr = wave * 16 + ln;
    const int base_f = rr * 32;
    const int sA = (((quad * 2)     ^ (rr & 7)) * 4);
    const int sB = (((quad * 2 + 1) ^ (rr & 7)) * 4);

    const unsigned short* wbase = Wf + lane * 8;

    f32x4 acc[8];
#pragma unroll
    for (int nt = 0; nt < 8; ++nt) acc[nt] = (f32x4){0.f, 0.f, 0.f, 0.f};

    // prologue: stage substeps 0,1 into buf0; load B frags for ks=0
    gload_lds16(gsrc0,      &Abuf[0][wave * 256]);
    gload_lds16(gsrc1,      &Abuf[0][1024 + wave * 256]);
    gload_lds16(gsrc0 + 32, &Abuf[0][2048 + wave * 256]);
    gload_lds16(gsrc1 + 32, &Abuf[0][3072 + wave * 256]);
    bf16x8 bfr[2][8];
#pragma unroll
    for (int nt = 0; nt < 8; ++nt) bfr[0][nt] = *(const bf16x8*)(wbase + nt * 512);

#pragma unroll
    for (int ks = 0; ks < NSTEP; ++ks) {
        const int sub  = ks & 1;             // substep within BK=64
        const int cbuf = (ks >> 1) & 1;      // LDS buffer
        const int bsel = ks & 1;             // rolling B-frag buffer
        if (sub == 0) {
            // barrier drains vmcnt(0): stage(kb) loads issued a full BK-iter ago are in
            __syncthreads();
            if (ks + 2 < NSTEP) {
                const float* n0 = gsrc0 + (size_t)(ks + 2) * 32;
                const float* n1 = gsrc1 + (size_t)(ks + 2) * 32;
                float* db = &Abuf[cbuf ^ 1][wave * 256];
                gload_lds16(n0,      db);
                gload_lds16(n1,      db + 1024);
                gload_lds16(n0 + 32, db + 2048);
                gload_lds16(n1 + 32, db + 3072);
            }
        }

        const float* fb_base = &Abuf[cbuf][sub * 2048 + base_f];
        float4 fa = *(const float4*)(fb_base + sA);
        float4 fb = *(const float4*)(fb_base + sB);
        float va[8] = {fa.x, fa.y, fa.z, fa.w, fb.x, fb.y, fb.z, fb.w};
        if (AFFINE) {
            const int kk = ks * 32 + quad * 8;
            const float4 s0 = *(const float4*)(sc + kk), s1 = *(const float4*)(sc + kk + 4);
            const float4 h0 = *(const float4*)(sh + kk), h1 = *(const float4*)(sh + kk + 4);
            va[0] = fmaxf(fmaf(s0.x, va[0], h0.x), 0.f);
            va[1] = fmaxf(fmaf(s0.y, va[1], h0.y), 0.f);
            va[2] = fmaxf(fmaf(s0.z, va[2], h0.z), 0.f);
            va[3] = fmaxf(fmaf(s0.w, va[3], h0.w), 0.f);
            va[4] = fmaxf(fmaf(s1.x, va[4], h1.x), 0.f);
            va[5] = fmaxf(fmaf(s1.y, va[5], h1.y), 0.f);
            va[6] = fmaxf(fmaf(s1.z, va[6], h1.z), 0.f);
            va[7] = fmaxf(fmaf(s1.w, va[7], h1.w), 0.f);
        }
        union { bf16x8 v; unsigned short u[8]; } af;
#pragma unroll
        for (int j = 0; j < 8; ++j) af.u[j] = (unsigned short)f2bf(va[j]);

        // prefetch next substep's B-frags (L2-hot; in flight across this step's MFMAs)
        if (ks + 1 < NSTEP) {
            const unsigned short* wfp = wbase + (size_t)(ks + 1) * 4096;
#pragma unroll
            for (int nt = 0; nt < 8; ++nt)
                bfr[bsel ^ 1][nt] = *(const bf16x8*)(wfp + nt * 512);
        }

#pragma unroll
        for (int nt = 0; nt < 8; ++nt)
            acc[nt] = __builtin_amdgcn_mfma_f32_16x16x32_bf16(af.v, bfr[bsel][nt], acc[nt], 0, 0, 0);
    }

    // epilogue: pack bf16 pairs + fused attention logits; C/D layout col=ln, row=quad*4+r
    float wsv[8], wdv[8];
#pragma unroll
    for (int nt = 0; nt < 8; ++nt) { wsv[nt] = atts[nt * 16 + ln]; wdv[nt] = attd[nt * 16 + ln]; }

    const int mbase = m0 + wave * 16 + quad * 4;
#pragma unroll
    for (int r = 0; r < 4; ++r) {
        int m = mbase + r;
        bool ok = (m < NN);
        float ps0 = 0.f, ps1 = 0.f, pd0 = 0.f, pd1 = 0.f;
#pragma unroll
        for (int nt = 0; nt < 8; ++nt) {
            float v = acc[nt][r];
            if (nt < 4) { ps0 = fmaf(v, wsv[nt], ps0); pd0 = fmaf(v, wdv[nt], pd0); }
            else        { ps1 = fmaf(v, wsv[nt], ps1); pd1 = fmaf(v, wdv[nt], pd1); }
        }
#pragma unroll
        for (int nt = 0; nt < 4; ++nt) {
            unsigned pk = f2bf(acc[nt][r]) | (f2bf(acc[nt + 4][r]) << 16);
            if (ok) hb[(size_t)m * 64 + nt * 16 + ln] = pk;
        }
#pragma unroll
        for (int o = 8; o > 0; o >>= 1) {
            ps0 += __shfl_down(ps0, o); ps1 += __shfl_down(ps1, o);
            pd0 += __shfl_down(pd0, o); pd1 += __shfl_down(pd1, o);
        }
        if (ok && ln == 0) {
            *(float2*)&as_[m * 2] = make_float2(ps0, ps1);
            *(float2*)&ad_[m * 2] = make_float2(pd0, pd1);
        }
    }
}

// ================= fused segment-softmax + aggregate + BN-stats partials =============
// TWO nodes per wave: each 32-lane half owns one node; every serial-loop instruction
// (bpermute broadcast, uint2 gather, FMA) serves two edges at once. Trip counts are
// wave-uniform (max over halves via shfl_xor 32); out-of-range lanes carry p=0 so
// their FMAs contribute zero — no exec divergence, all bpermute sources stay active.
__global__ __launch_bounds__(256) void gat_agg_kernel(
    const int* __restrict__ rowp, const int* __restrict__ esrc,
    const float* __restrict__ as_, const float* __restrict__ ad_,
    const unsigned* __restrict__ hb, float* __restrict__ out,
    float* __restrict__ stats)
{
    const int tid  = threadIdx.x;
    const int wave = tid >> 6;
    const int lane = tid & 63;
    const int half = lane >> 5;          // which node of the pair
    const int hl   = lane & 31;          // lane within half
    const int node = blockIdx.x * 8 + wave * 2 + half;   // 8 nodes/block, grid 6250

    const int beg = rowp[node], end = rowp[node + 1];
    float2 adv = *(const float2*)&ad_[node * 2];

    const int deg = end - beg;
    const int degmax = max(deg, __shfl_xor(deg, 32));
    const int nchunk = (degmax + 31) >> 5;
    const int sb = half * 32;
    const unsigned* hbp = hb + 2 * hl;   // this lane's 2 uints (cols 2hl,2hl+1 / +64)

    float l0 = 0.f, l1 = 0.f;
    float a00 = 0.f, a01 = 0.f, a10 = 0.f, a11 = 0.f;

    for (int c = 0; c < nchunk; ++c) {
        int j0 = beg + c * 32;
        int sl = 0; float p0l = 0.f, p1l = 0.f;
        if (j0 + hl < end) {
            sl = esrc[j0 + hl];
            float2 t = *(const float2*)&as_[sl * 2];
            float e0 = t.x + adv.x; e0 = fmaxf(e0, NEG_SLOPE * e0);
            float e1 = t.y + adv.y; e1 = fmaxf(e1, NEG_SLOPE * e1);
            p0l = __expf(e0); p1l = __expf(e1);
        }
        l0 += p0l; l1 += p1l;            // per-lane partial denominator

        int nj = end - j0; nj = nj < 0 ? 0 : (nj > 32 ? 32 : nj);
        int njmax = max(nj, __shfl_xor(nj, 32));

        int j = 0;
        for (; j + 8 <= njmax; j += 8) {
            uint2 u[8]; float p0[8], p1[8];
#pragma unroll
            for (int q = 0; q < 8; ++q) {
                int s  = __shfl(sl, sb + j + q);
                p0[q]  = __shfl(p0l, sb + j + q);
                p1[q]  = __shfl(p1l, sb + j + q);
                u[q]   = *(const uint2*)(hbp + (size_t)s * 64);
            }
#pragma unroll
            for (int q = 0; q < 8; ++q) {
                a00 = fmaf(p0[q], __uint_as_float(u[q].x << 16), a00);
                a10 = fmaf(p1[q], __uint_as_float(u[q].x & 0xffff0000u), a10);
                a01 = fmaf(p0[q], __uint_as_float(u[q].y << 16), a01);
                a11 = fmaf(p1[q], __uint_as_float(u[q].y & 0xffff0000u), a11);
            }
        }
        for (; j < njmax; ++j) {
            int s  = __shfl(sl, sb + j);
            float p0 = __shfl(p0l, sb + j);
            float p1 = __shfl(p1l, sb + j);
            uint2 u = *(const uint2*)(hbp + (size_t)s * 64);
            a00 = fmaf(p0, __uint_as_float(u.x << 16), a00);
            a10 = fmaf(p1, __uint_as_float(u.x & 0xffff0000u), a10);
            a01 = fmaf(p0, __uint_as_float(u.y << 16), a01);
            a11 = fmaf(p1, __uint_as_float(u.y & 0xffff0000u), a11);
        }
    }

#pragma unroll
    for (int o = 1; o < 32; o <<= 1) {
        l0 += __shfl_xor(l0, o); l1 += __shfl_xor(l1, o);
    }
    float r0 = 1.f / l0, r1 = 1.f / l1;
    float v00 = a00 * r0, v01 = a01 * r0, v10 = a10 * r1, v11 = a11 * r1;
    *(float2*)&out[(size_t)node * HC + 2 * hl]      = make_float2(v00, v01);
    *(float2*)&out[(size_t)node * HC + 64 + 2 * hl] = make_float2(v10, v11);

    // ---- fused BN-stats partials (8 nodes/block) ----
    __shared__ float red[8][128];
    const int w2 = wave * 2 + half;
    red[w2][2 * hl]      = v00;  red[w2][2 * hl + 1]      = v01;
    red[w2][64 + 2 * hl] = v10;  red[w2][64 + 2 * hl + 1] = v11;
    __syncthreads();
    if (tid < 128) {
        float s = 0.f, q = 0.f;
#pragma unroll
        for (int w = 0; w < 8; ++w) {
            float v = red[w][tid];
            s += v; q = fmaf(v, v, q);
        }
        int slot = blockIdx.x & 63;
        atomicAdd(&stats[slot * 128 + tid], s);
        atomicAdd(&stats[64 * 128 + slot * 128 + tid], q);
    }
}

// ================= BN params: reduce 64 stat slices =================
__global__ void bn_params_kernel(
    const float* __restrict__ stats, const float* __restrict__ gamma,
    const float* __restrict__ beta, float* __restrict__ sc, float* __restrict__ sh)
{
    int c = threadIdx.x;                  // 128 threads
    float su = 0.f, sq = 0.f;
#pragma unroll
    for (int k = 0; k < 64; ++k) {
        su += stats[k * 128 + c];
        sq += stats[64 * 128 + k * 128 + c];
    }
    const float inv_n = 1.0f / (float)NN;
    float mu = su * inv_n;
    float var = sq * inv_n - mu * mu;
    float rs = rsqrtf(var + BN_EPS);
    float s = gamma[c] * rs;
    sc[c] = s;
    sh[c] = beta[c] - mu * s;
}

// ================= pool: 64 rows/block (782 blocks), flush-on-graph-change =================
__global__ __launch_bounds__(256) void pool_kernel(
    const float* __restrict__ x, const float* __restrict__ sc,
    const float* __restrict__ sh, const int* __restrict__ batch,
    float* __restrict__ pool, float* __restrict__ cnt)
{
    int c = threadIdx.x & 127;
    int half = threadIdx.x >> 7;
    int r0 = blockIdx.x * 64;
    int rend = min(r0 + 64, NN);
    float s = sc[c], b = sh[c];
    int cur = -1; float acc = 0.f, ccount = 0.f;
    for (int r = r0 + half; r < rend; r += 2) {
        int g = batch[r];
        if (g != cur) {
            if (cur >= 0) {
                atomicAdd(&pool[cur * HC + c], acc);
                if (c == 0) atomicAdd(&cnt[cur], ccount);
            }
            cur = g; acc = 0.f; ccount = 0.f;
        }
        float v = x[(size_t)r * HC + c];
        acc += fmaxf(fmaf(s, v, b), 0.f);
        ccount += 1.f;
    }
    if (cur >= 0) {
        atomicAdd(&pool[cur * HC + c], acc);
        if (c == 0) atomicAdd(&cnt[cur], ccount);
    }
}

// ================= final linear: [64,128]@[128,2] + blin =================
__global__ void final_kernel(
    const float* __restrict__ pool, const float* __restrict__ cnt,
    const float* __restrict__ Wlin, const float* __restrict__ blin,
    float* __restrict__ outp)
{
    int t = threadIdx.x;               // 128 threads
    int b = t >> 1, oc = t & 1;
    float inv = 1.f / fmaxf(cnt[b], 1.f);
    float s = blin[oc];
    for (int c = 0; c < HC; ++c)
        s += pool[b * HC + c] * inv * Wlin[c * 2 + oc];
    outp[b * 2 + oc] = s;
}

// ================= workspace layout =================
// floats
static constexpr size_t OFF_OUT   = 0;                        // [N*HC]
static constexpr size_t OFF_AS    = OFF_OUT + (size_t)NN*HC;  // [N*2]
static constexpr size_t OFF_AD    = OFF_AS  + (size_t)NN*HH;
static constexpr size_t OFF_ST1   = OFF_AD  + (size_t)NN*HH;  // zero from here: [2*64*128]
static constexpr size_t OFF_ST2   = OFF_ST1 + 2*64*128;
static constexpr size_t OFF_SC1   = OFF_ST2 + 2*64*128;       // [128]
static constexpr size_t OFF_SH1   = OFF_SC1 + 128;
static constexpr size_t OFF_SC2   = OFF_SH1 + 128;
static constexpr size_t OFF_SH2   = OFF_SC2 + 128;
static constexpr size_t OFF_POOL  = OFF_SH2 + 128;            // [B*HC]
static constexpr size_t OFF_CNT   = OFF_POOL+ (size_t)BB*HC;  // [B]
static constexpr size_t OFF_ZEND  = OFF_CNT + BB;             // end of zeroed float region
// ints (after float region) — deg FIRST so one memset covers floats+deg
static constexpr size_t IOFF_DEG  = 0;                        // [N]  (zeroed)
static constexpr size_t IOFF_ROWP = IOFF_DEG  + NN;           // [N+1]
static constexpr size_t IOFF_CUR  = IOFF_ROWP + NN + 1;       // [N]
static constexpr size_t IOFF_BSUM = IOFF_CUR  + NN;           // [NBLK_SCAN]
static constexpr size_t IOFF_BOFS = IOFF_BSUM + NBLK_SCAN;    // [NBLK_SCAN]
static constexpr size_t IOFF_ESRC = IOFF_BOFS + NBLK_SCAN;    // [ETOT]
static constexpr size_t IOFF_HB   = (IOFF_ESRC + ETOT + 3) & ~(size_t)3;  // [N*64] uints
static constexpr size_t IOFF_WF1  = IOFF_HB + (size_t)NN*64;  // [512*64] ints
static constexpr size_t IOFF_WF2  = IOFF_WF1 + (size_t)IN_C*64; // [128*64] ints
static constexpr size_t IOFF_END  = IOFF_WF2 + (size_t)HC*64;

extern "C" void kernel_launch(void* const* d_in, const int* in_sizes, int n_in,
                              void* d_out, int out_size, void* d_ws, size_t ws_size,
                              hipStream_t stream)
{
    const float* x       = (const float*)d_in[0];
    const int*   ei      = (const int*)  d_in[1];
    const int*   batch   = (const int*)  d_in[2];
    const float* W1      = (const float*)d_in[3];
    const float* atts1   = (const float*)d_in[4];
    const float* attd1   = (const float*)d_in[5];
    const float* gamma1  = (const float*)d_in[7];
    const float* beta1   = (const float*)d_in[8];
    const float* W2      = (const float*)d_in[9];
    const float* atts2   = (const float*)d_in[10];
    const float* attd2   = (const float*)d_in[11];
    const float* gamma2  = (const float*)d_in[13];
    const float* beta2   = (const float*)d_in[14];
    const float* Wlin    = (const float*)d_in[15];
    const float* blin    = (const float*)d_in[16];
    float* outp = (float*)d_out;

    float* ws    = (float*)d_ws;
    float* out   = ws + OFF_OUT;
    float* as_   = ws + OFF_AS;
    float* ad_   = ws + OFF_AD;
    float* st1   = ws + OFF_ST1;
    float* st2   = ws + OFF_ST2;
    float* sc1   = ws + OFF_SC1;
    float* sh1   = ws + OFF_SH1;
    float* sc2   = ws + OFF_SC2;
    float* sh2   = ws + OFF_SH2;
    float* pool  = ws + OFF_POOL;
    float* cnt   = ws + OFF_CNT;

    int* iws  = (int*)(ws + OFF_ZEND);
    int* deg  = iws + IOFF_DEG;
    int* rowp = iws + IOFF_ROWP;
    int* curp = iws + IOFF_CUR;
    int* bsum = iws + IOFF_BSUM;
    int* bofs = iws + IOFF_BOFS;
    int* esrc = iws + IOFF_ESRC;
    unsigned* hb = (unsigned*)(iws + IOFF_HB);
    unsigned short* Wf1 = (unsigned short*)(iws + IOFF_WF1);
    unsigned short* Wf2 = (unsigned short*)(iws + IOFF_WF2);

    const int BIN_BLK   = NXCD * NSLOT;          // 8 * 416 = 3328
    const int GEMM_BLK  = (NN + 63) / 64;        // 782: 64 rows x 128 cols
    const int WAVE_BLK  = NN / 8;                // 6250: 8 nodes/block (2 per wave)
    const int POOL_BLK  = (NN + 63) / 64;        // 782: 64 rows/block
    const int WFRG_BLK  = (IN_C * 16 + HC * 16 + 255) / 256;  // 40

    // single memset: bn-stats/sc-sh/pool/cnt float region + deg (contiguous)
    hipMemsetAsync(st1, 0, (OFF_ZEND - OFF_ST1) * sizeof(float) + NN * sizeof(int), stream);

    // ----- weight fragment packs + CSR build (shared by both layers) -----
    wfrag_kernel<<<WFRG_BLK, 256, 0, stream>>>(W1, Wf1, W2, Wf2);
    deg_kernel<<<BIN_BLK, 256, 0, stream>>>(ei, deg);
    bsum_kernel<<<NBLK_SCAN, 256, 0, stream>>>(deg, bsum);
    bscan_kernel<<<1, 256, 0, stream>>>(bsum, bofs, rowp);
    bapply_kernel<<<NBLK_SCAN, 256, 0, stream>>>(deg, bofs, rowp, curp);
    scatter_kernel<<<BIN_BLK, 256, 0, stream>>>(ei, curp, esrc);

    // ----- layer 1 (GEMM + fused alpha + bf16 pack; agg + fused BN stats) -----
    mfma_gemm_kernel<IN_C, false><<<GEMM_BLK, 256, 0, stream>>>(
        x, Wf1, atts1, attd1, hb, as_, ad_, nullptr, nullptr);
    gat_agg_kernel<<<WAVE_BLK, 256, 0, stream>>>(rowp, esrc, as_, ad_, hb, out, st1);
    bn_params_kernel<<<1, 128, 0, stream>>>(st1, gamma1, beta1, sc1, sh1);

    // ----- layer 2 (BN1-affine+ReLU fused into GEMM2 A-load) -----
    mfma_gemm_kernel<HC, true><<<GEMM_BLK, 256, 0, stream>>>(
        out, Wf2, atts2, attd2, hb, as_, ad_, sc1, sh1);
    gat_agg_kernel<<<WAVE_BLK, 256, 0, stream>>>(rowp, esrc, as_, ad_, hb, out, st2);
    bn_params_kernel<<<1, 128, 0, stream>>>(st2, gamma2, beta2, sc2, sh2);

    // ----- pool + final linear -----
    pool_kernel<<<POOL_BLK, 256, 0, stream>>>(out, sc2, sh2, batch, pool, cnt);
    final_kernel<<<1, 128, 0, stream>>>(pool, cnt, Wlin, blin, outp);
}

// Round 9
// 413.862 us; speedup vs baseline: 1.2992x; 1.0088x over previous
//
#include <hip/hip_runtime.h>
#include <hip/hip_bf16.h>
#include <cstdint>
#include <cstddef>

// Problem constants (match reference)
#define NN      50000
#define IN_C    512
#define EE      800000
#define ETOT    850000      // E + N self-loops
#define HH      2
#define CC      64
#define HC      128
#define BB      64
#define OUTC    2
#define NEG_SLOPE 0.2f
#define BN_EPS  1e-5f

#define NBLK_SCAN ((NN + 255) / 256)   // 196

// XCD binning for CSR build: 8 dst ranges, blockIdx%8 -> XCD (round-robin dispatch)
#define NXCD     8
#define NPX      ((NN + NXCD - 1) / NXCD)        // 6250 nodes per bin
#define EDGES_PER_SLOT 2048
#define NSLOT    ((ETOT + EDGES_PER_SLOT - 1) / EDGES_PER_SLOT)  // 416
#define WFRG_BLKS ((IN_C * 16 + HC * 16 + 255) / 256)            // 40

typedef __bf16 bf16x8 __attribute__((ext_vector_type(8)));
typedef float  f32x4  __attribute__((ext_vector_type(4)));

__device__ __forceinline__ unsigned f2bf(float f) {
    __bf16 b = (__bf16)f;                      // RNE convert
    return (unsigned)__builtin_bit_cast(unsigned short, b);
}

// async global->LDS, 16B per lane; LDS dest is wave-uniform base + lane*16
__device__ __forceinline__ void gload_lds16(const float* g, float* l) {
    __builtin_amdgcn_global_load_lds(
        (const __attribute__((address_space(1))) unsigned*)g,
        (__attribute__((address_space(3))) unsigned*)l,
        16, 0, 0);
}

// ================= fused weight-pack + degree count (block-range split) =================
// Blocks [0,40): W -> bf16 MFMA fragment order. Blocks [40, 40+3328): XCD-binned degree.
__global__ __launch_bounds__(256) void prep_kernel(
    const float* __restrict__ W1, unsigned short* __restrict__ Wf1,
    const float* __restrict__ W2, unsigned short* __restrict__ Wf2,
    const int* __restrict__ ei, int* __restrict__ deg)
{
    if (blockIdx.x < WFRG_BLKS) {
        int t = blockIdx.x * 256 + threadIdx.x;
        const float* W; unsigned short* Wf;
        if (t < IN_C * 16) { W = W1; Wf = Wf1; }
        else {
            t -= IN_C * 16;
            if (t >= HC * 16) return;
            W = W2; Wf = Wf2;
        }
        int lane = t & 63, frag = t >> 6;
        int kblk = frag >> 3, nt = frag & 7;
        int quad = lane >> 4, ln = lane & 15;
        int kbase = kblk * 32 + quad * 8;
        int n = nt * 16 + ln;
        unsigned short u[8];
#pragma unroll
        for (int j = 0; j < 8; ++j)
            u[j] = (unsigned short)f2bf(W[(size_t)(kbase + j) * HC + n]);
        ushort4 a; a.x = u[0]; a.y = u[1]; a.z = u[2]; a.w = u[3];
        ushort4 b; b.x = u[4]; b.y = u[5]; b.z = u[6]; b.w = u[7];
        *(ushort4*)(Wf + (size_t)t * 8)     = a;
        *(ushort4*)(Wf + (size_t)t * 8 + 4) = b;
        return;
    }
    const int bid  = blockIdx.x - WFRG_BLKS;
    const int xcd  = bid & (NXCD - 1);
    const int slot = bid >> 3;
    const int lo = xcd * NPX, hi = lo + NPX;
    const int base = slot * EDGES_PER_SLOT;
#pragma unroll
    for (int it = 0; it < EDGES_PER_SLOT / 256; ++it) {
        int e = base + it * 256 + threadIdx.x;
        if (e < ETOT) {
            int d = (e < EE) ? ei[EE + e] : (e - EE);
            if (d >= lo && d < hi) atomicAdd(&deg[d], 1);
        }
    }
}

// --- hierarchical scan (3 tiny kernels; single-block fusion was 15x slower, R6) ---
__global__ __launch_bounds__(256) void bsum_kernel(const int* __restrict__ deg, int* __restrict__ bsum)
{
    int i = blockIdx.x * 256 + threadIdx.x;
    int v = (i < NN) ? deg[i] : 0;
    int lane = threadIdx.x & 63, wv = threadIdx.x >> 6;
#pragma unroll
    for (int o = 32; o > 0; o >>= 1) v += __shfl_down(v, o);
    __shared__ int ws[4];
    if (lane == 0) ws[wv] = v;
    __syncthreads();
    if (threadIdx.x == 0) bsum[blockIdx.x] = ws[0] + ws[1] + ws[2] + ws[3];
}

__global__ __launch_bounds__(256) void bscan_kernel(
    const int* __restrict__ bsum, int* __restrict__ bofs, int* __restrict__ rowp)
{
    int t = threadIdx.x;
    int lane = t & 63, wv = t >> 6;
    int v = (t < NBLK_SCAN) ? bsum[t] : 0;
    int x = v;
#pragma unroll
    for (int o = 1; o < 64; o <<= 1) {
        int y = __shfl_up(x, o);
        if (lane >= o) x += y;
    }
    __shared__ int ws[4];
    if (lane == 63) ws[wv] = x;
    __syncthreads();
    int wo = 0;
#pragma unroll
    for (int w = 0; w < 4; ++w) if (w < wv) wo += ws[w];
    if (t < NBLK_SCAN) bofs[t] = x + wo - v;     // exclusive
    if (t == 0) rowp[NN] = ETOT;
}

__global__ __launch_bounds__(256) void bapply_kernel(
    const int* __restrict__ deg, const int* __restrict__ bofs,
    int* __restrict__ rowp, int* __restrict__ cur)
{
    int i = blockIdx.x * 256 + threadIdx.x;
    int v = (i < NN) ? deg[i] : 0;
    int lane = threadIdx.x & 63, wv = threadIdx.x >> 6;
    int x = v;
#pragma unroll
    for (int o = 1; o < 64; o <<= 1) {
        int y = __shfl_up(x, o);
        if (lane >= o) x += y;
    }
    __shared__ int ws[4];
    if (lane == 63) ws[wv] = x;
    __syncthreads();
    int wo = 0;
#pragma unroll
    for (int w = 0; w < 4; ++w) if (w < wv) wo += ws[w];
    if (i < NN) {
        int r = bofs[blockIdx.x] + x + wo - v;   // exclusive global
        rowp[i] = r; cur[i] = r;
    }
}

__global__ __launch_bounds__(256) void scatter_kernel(
    const int* __restrict__ ei, int* __restrict__ cur, int* __restrict__ esrc)
{
    const int xcd  = blockIdx.x & (NXCD - 1);
    const int slot = blockIdx.x >> 3;
    const int lo = xcd * NPX, hi = lo + NPX;
    const int base = slot * EDGES_PER_SLOT;
#pragma unroll
    for (int it = 0; it < EDGES_PER_SLOT / 256; ++it) {
        int e = base + it * 256 + threadIdx.x;
        if (e < ETOT) {
            int s, d;
            if (e < EE) { s = ei[e]; d = ei[EE + e]; }
            else        { s = e - EE; d = s; }
            if (d >= lo && d < hi) {
                int pos = atomicAdd(&cur[d], 1);
                esrc[pos] = s;
            }
        }
    }
}

// ================= LDS-staged MFMA GEMM, BK=64 per barrier (R4-measured form) =========
// Block = 64 rows x 128 cols, 4 waves. A staged via global_load_lds into a 2 x 16 KB
// double buffer, TWO 32-wide K-substeps per barrier. LDS sub-tile [64][32] XOR-swizzled
// via pre-swizzled global source (rule 21). B streamed from L2 in regs, double-buffered.
template<int K, bool AFFINE>
__global__ __launch_bounds__(256) void mfma_gemm_kernel(
    const float* __restrict__ A, const unsigned short* __restrict__ Wf,
    const float* __restrict__ atts, const float* __restrict__ attd,
    unsigned* __restrict__ hb, float* __restrict__ as_, float* __restrict__ ad_,
    const float* __restrict__ sc, const float* __restrict__ sh)
{
    constexpr int NSTEP = K >> 5;                   // 32-wide substeps
    __shared__ __align__(16) float Abuf[2][64 * 64]; // 2 x 16 KB

    const int tid  = threadIdx.x;
    const int wave = tid >> 6, lane = tid & 63;
    const int quad = lane >> 4, ln = lane & 15;
    const int m0 = blockIdx.x * 64;

    // staging geometry: thread t covers 16B slot (row t>>3, slot t&7), rows +0/+32
    const int srow = tid >> 3;
    const int g    = (tid & 7) ^ (srow & 7);        // swizzled source slot
    int grow0 = m0 + srow;      if (grow0 > NN - 1) grow0 = NN - 1;
    int grow1 = m0 + srow + 32; if (grow1 > NN - 1) grow1 = NN - 1;
    const float* gsrc0 = A + (size_t)grow0 * K + g * 4;
    const float* gsrc1 = A + (size_t)grow1 * K + g * 4;

    // fragment-read geometry
    const int rr = wave * 16 + ln;
    const int base_f = rr * 32;
    const int sA = (((quad * 2)     ^ (rr & 7)) * 4);
    const int sB = (((quad * 2 + 1) ^ (rr & 7)) * 4);

    const unsigned short* wbase = Wf + lane * 8;

    f32x4 acc[8];
#pragma unroll
    for (int nt = 0; nt < 8; ++nt) acc[nt] = (f32x4){0.f, 0.f, 0.f, 0.f};

    // prologue: stage substeps 0,1 into buf0; load B frags for ks=0
    gload_lds16(gsrc0,      &Abuf[0][wave * 256]);
    gload_lds16(gsrc1,      &Abuf[0][1024 + wave * 256]);
    gload_lds16(gsrc0 + 32, &Abuf[0][2048 + wave * 256]);
    gload_lds16(gsrc1 + 32, &Abuf[0][3072 + wave * 256]);
    bf16x8 bfr[2][8];
#pragma unroll
    for (int nt = 0; nt < 8; ++nt) bfr[0][nt] = *(const bf16x8*)(wbase + nt * 512);

#pragma unroll
    for (int ks = 0; ks < NSTEP; ++ks) {
        const int sub  = ks & 1;             // substep within BK=64
        const int cbuf = (ks >> 1) & 1;      // LDS buffer
        const int bsel = ks & 1;             // rolling B-frag buffer
        if (sub == 0) {
            // barrier drains vmcnt(0): stage(kb) loads issued a full BK-iter ago are in
            __syncthreads();
            if (ks + 2 < NSTEP) {
                const float* n0 = gsrc0 + (size_t)(ks + 2) * 32;
                const float* n1 = gsrc1 + (size_t)(ks + 2) * 32;
                float* db = &Abuf[cbuf ^ 1][wave * 256];
                gload_lds16(n0,      db);
                gload_lds16(n1,      db + 1024);
                gload_lds16(n0 + 32, db + 2048);
                gload_lds16(n1 + 32, db + 3072);
            }
        }

        const float* fb_base = &Abuf[cbuf][sub * 2048 + base_f];
        float4 fa = *(const float4*)(fb_base + sA);
        float4 fb = *(const float4*)(fb_base + sB);
        float va[8] = {fa.x, fa.y, fa.z, fa.w, fb.x, fb.y, fb.z, fb.w};
        if (AFFINE) {
            const int kk = ks * 32 + quad * 8;
            const float4 s0 = *(const float4*)(sc + kk), s1 = *(const float4*)(sc + kk + 4);
            const float4 h0 = *(const float4*)(sh + kk), h1 = *(const float4*)(sh + kk + 4);
            va[0] = fmaxf(fmaf(s0.x, va[0], h0.x), 0.f);
            va[1] = fmaxf(fmaf(s0.y, va[1], h0.y), 0.f);
            va[2] = fmaxf(fmaf(s0.z, va[2], h0.z), 0.f);
            va[3] = fmaxf(fmaf(s0.w, va[3], h0.w), 0.f);
            va[4] = fmaxf(fmaf(s1.x, va[4], h1.x), 0.f);
            va[5] = fmaxf(fmaf(s1.y, va[5], h1.y), 0.f);
            va[6] = fmaxf(fmaf(s1.z, va[6], h1.z), 0.f);
            va[7] = fmaxf(fmaf(s1.w, va[7], h1.w), 0.f);
        }
        union { bf16x8 v; unsigned short u[8]; } af;
#pragma unroll
        for (int j = 0; j < 8; ++j) af.u[j] = (unsigned short)f2bf(va[j]);

        // prefetch next substep's B-frags (L2-hot; in flight across this step's MFMAs)
        if (ks + 1 < NSTEP) {
            const unsigned short* wfp = wbase + (size_t)(ks + 1) * 4096;
#pragma unroll
            for (int nt = 0; nt < 8; ++nt)
                bfr[bsel ^ 1][nt] = *(const bf16x8*)(wfp + nt * 512);
        }

#pragma unroll
        for (int nt = 0; nt < 8; ++nt)
            acc[nt] = __builtin_amdgcn_mfma_f32_16x16x32_bf16(af.v, bfr[bsel][nt], acc[nt], 0, 0, 0);
    }

    // epilogue: pack bf16 pairs + fused attention logits; C/D layout col=ln, row=quad*4+r
    float wsv[8], wdv[8];
#pragma unroll
    for (int nt = 0; nt < 8; ++nt) { wsv[nt] = atts[nt * 16 + ln]; wdv[nt] = attd[nt * 16 + ln]; }

    const int mbase = m0 + wave * 16 + quad * 4;
#pragma unroll
    for (int r = 0; r < 4; ++r) {
        int m = mbase + r;
        bool ok = (m < NN);
        float ps0 = 0.f, ps1 = 0.f, pd0 = 0.f, pd1 = 0.f;
#pragma unroll
        for (int nt = 0; nt < 8; ++nt) {
            float v = acc[nt][r];
            if (nt < 4) { ps0 = fmaf(v, wsv[nt], ps0); pd0 = fmaf(v, wdv[nt], pd0); }
            else        { ps1 = fmaf(v, wsv[nt], ps1); pd1 = fmaf(v, wdv[nt], pd1); }
        }
#pragma unroll
        for (int nt = 0; nt < 4; ++nt) {
            unsigned pk = f2bf(acc[nt][r]) | (f2bf(acc[nt + 4][r]) << 16);
            if (ok) hb[(size_t)m * 64 + nt * 16 + ln] = pk;
        }
#pragma unroll
        for (int o = 8; o > 0; o >>= 1) {
            ps0 += __shfl_down(ps0, o); ps1 += __shfl_down(ps1, o);
            pd0 += __shfl_down(pd0, o); pd1 += __shfl_down(pd1, o);
        }
        if (ok && ln == 0) {
            *(float2*)&as_[m * 2] = make_float2(ps0, ps1);
            *(float2*)&ad_[m * 2] = make_float2(pd0, pd1);
        }
    }
}

// ================= fused segment-softmax + aggregate + BN-stats partials =============
// TWO nodes per wave (32-lane half = one node). Gather MLP deepened to 16: all 16
// uint2 gathers of a batch issue before any consume — the typical node (deg~17) runs
// ONE latency group instead of 2-3. p-broadcasts re-issued in the consume phase to
// keep register pressure ~55 VGPR (8 waves/SIMD).
__global__ __launch_bounds__(256) void gat_agg_kernel(
    const int* __restrict__ rowp, const int* __restrict__ esrc,
    const float* __restrict__ as_, const float* __restrict__ ad_,
    const unsigned* __restrict__ hb, float* __restrict__ out,
    float* __restrict__ stats)
{
    const int tid  = threadIdx.x;
    const int wave = tid >> 6;
    const int lane = tid & 63;
    const int half = lane >> 5;          // which node of the pair
    const int hl   = lane & 31;          // lane within half
    const int node = blockIdx.x * 8 + wave * 2 + half;   // 8 nodes/block, grid 6250

    const int beg = rowp[node], end = rowp[node + 1];
    float2 adv = *(const float2*)&ad_[node * 2];

    const int deg = end - beg;
    const int degmax = max(deg, __shfl_xor(deg, 32));
    const int nchunk = (degmax + 31) >> 5;
    const int sb = half * 32;
    const unsigned* hbp = hb + 2 * hl;   // this lane's 2 uints (cols 2hl,2hl+1 / +64)

    float l0 = 0.f, l1 = 0.f;
    float a00 = 0.f, a01 = 0.f, a10 = 0.f, a11 = 0.f;

    for (int c = 0; c < nchunk; ++c) {
        int j0 = beg + c * 32;
        int sl = 0; float p0l = 0.f, p1l = 0.f;
        if (j0 + hl < end) {
            sl = esrc[j0 + hl];
            float2 t = *(const float2*)&as_[sl * 2];
            float e0 = t.x + adv.x; e0 = fmaxf(e0, NEG_SLOPE * e0);
            float e1 = t.y + adv.y; e1 = fmaxf(e1, NEG_SLOPE * e1);
            p0l = __expf(e0); p1l = __expf(e1);
        }
        l0 += p0l; l1 += p1l;            // per-lane partial denominator

        int nj = end - j0; nj = nj < 0 ? 0 : (nj > 32 ? 32 : nj);
        int njmax = max(nj, __shfl_xor(nj, 32));

        int j = 0;
        for (; j + 16 <= njmax; j += 16) {
            uint2 u[16];
#pragma unroll
            for (int q = 0; q < 16; ++q) {
                int s = __shfl(sl, sb + j + q);
                u[q]  = *(const uint2*)(hbp + (size_t)s * 64);
            }
#pragma unroll
            for (int q = 0; q < 16; ++q) {
                float p0 = __shfl(p0l, sb + j + q);
                float p1 = __shfl(p1l, sb + j + q);
                a00 = fmaf(p0, __uint_as_float(u[q].x << 16), a00);
                a10 = fmaf(p1, __uint_as_float(u[q].x & 0xffff0000u), a10);
                a01 = fmaf(p0, __uint_as_float(u[q].y << 16), a01);
                a11 = fmaf(p1, __uint_as_float(u[q].y & 0xffff0000u), a11);
            }
        }
        for (; j + 4 <= njmax; j += 4) {
            uint2 u[4];
#pragma unroll
            for (int q = 0; q < 4; ++q) {
                int s = __shfl(sl, sb + j + q);
                u[q]  = *(const uint2*)(hbp + (size_t)s * 64);
            }
#pragma unroll
            for (int q = 0; q < 4; ++q) {
                float p0 = __shfl(p0l, sb + j + q);
                float p1 = __shfl(p1l, sb + j + q);
                a00 = fmaf(p0, __uint_as_float(u[q].x << 16), a00);
                a10 = fmaf(p1, __uint_as_float(u[q].x & 0xffff0000u), a10);
                a01 = fmaf(p0, __uint_as_float(u[q].y << 16), a01);
                a11 = fmaf(p1, __uint_as_float(u[q].y & 0xffff0000u), a11);
            }
        }
        for (; j < njmax; ++j) {
            int s  = __shfl(sl, sb + j);
            float p0 = __shfl(p0l, sb + j);
            float p1 = __shfl(p1l, sb + j);
            uint2 u = *(const uint2*)(hbp + (size_t)s * 64);
            a00 = fmaf(p0, __uint_as_float(u.x << 16), a00);
            a10 = fmaf(p1, __uint_as_float(u.x & 0xffff0000u), a10);
            a01 = fmaf(p0, __uint_as_float(u.y << 16), a01);
            a11 = fmaf(p1, __uint_as_float(u.y & 0xffff0000u), a11);
        }
    }

#pragma unroll
    for (int o = 1; o < 32; o <<= 1) {
        l0 += __shfl_xor(l0, o); l1 += __shfl_xor(l1, o);
    }
    float r0 = 1.f / l0, r1 = 1.f / l1;
    float v00 = a00 * r0, v01 = a01 * r0, v10 = a10 * r1, v11 = a11 * r1;
    *(float2*)&out[(size_t)node * HC + 2 * hl]      = make_float2(v00, v01);
    *(float2*)&out[(size_t)node * HC + 64 + 2 * hl] = make_float2(v10, v11);

    // ---- fused BN-stats partials (8 nodes/block) ----
    __shared__ float red[8][128];
    const int w2 = wave * 2 + half;
    red[w2][2 * hl]      = v00;  red[w2][2 * hl + 1]      = v01;
    red[w2][64 + 2 * hl] = v10;  red[w2][64 + 2 * hl + 1] = v11;
    __syncthreads();
    if (tid < 128) {
        float s = 0.f, q = 0.f;
#pragma unroll
        for (int w = 0; w < 8; ++w) {
            float v = red[w][tid];
            s += v; q = fmaf(v, v, q);
        }
        int slot = blockIdx.x & 63;
        atomicAdd(&stats[slot * 128 + tid], s);
        atomicAdd(&stats[64 * 128 + slot * 128 + tid], q);
    }
}

// ================= BN params: reduce 64 stat slices =================
__global__ void bn_params_kernel(
    const float* __restrict__ stats, const float* __restrict__ gamma,
    const float* __restrict__ beta, float* __restrict__ sc, float* __restrict__ sh)
{
    int c = threadIdx.x;                  // 128 threads
    float su = 0.f, sq = 0.f;
#pragma unroll
    for (int k = 0; k < 64; ++k) {
        su += stats[k * 128 + c];
        sq += stats[64 * 128 + k * 128 + c];
    }
    const float inv_n = 1.0f / (float)NN;
    float mu = su * inv_n;
    float var = sq * inv_n - mu * mu;
    float rs = rsqrtf(var + BN_EPS);
    float s = gamma[c] * rs;
    sc[c] = s;
    sh[c] = beta[c] - mu * s;
}

// ================= pool: 64 rows/block (782 blocks), flush-on-graph-change =================
__global__ __launch_bounds__(256) void pool_kernel(
    const float* __restrict__ x, const float* __restrict__ sc,
    const float* __restrict__ sh, const int* __restrict__ batch,
    float* __restrict__ pool, float* __restrict__ cnt)
{
    int c = threadIdx.x & 127;
    int half = threadIdx.x >> 7;
    int r0 = blockIdx.x * 64;
    int rend = min(r0 + 64, NN);
    float s = sc[c], b = sh[c];
    int cur = -1; float acc = 0.f, ccount = 0.f;
    for (int r = r0 + half; r < rend; r += 2) {
        int g = batch[r];
        if (g != cur) {
            if (cur >= 0) {
                atomicAdd(&pool[cur * HC + c], acc);
                if (c == 0) atomicAdd(&cnt[cur], ccount);
            }
            cur = g; acc = 0.f; ccount = 0.f;
        }
        float v = x[(size_t)r * HC + c];
        acc += fmaxf(fmaf(s, v, b), 0.f);
        ccount += 1.f;
    }
    if (cur >= 0) {
        atomicAdd(&pool[cur * HC + c], acc);
        if (c == 0) atomicAdd(&cnt[cur], ccount);
    }
}

// ================= final linear: [64,128]@[128,2] + blin =================
__global__ void final_kernel(
    const float* __restrict__ pool, const float* __restrict__ cnt,
    const float* __restrict__ Wlin, const float* __restrict__ blin,
    float* __restrict__ outp)
{
    int t = threadIdx.x;               // 128 threads
    int b = t >> 1, oc = t & 1;
    float inv = 1.f / fmaxf(cnt[b], 1.f);
    float s = blin[oc];
    for (int c = 0; c < HC; ++c)
        s += pool[b * HC + c] * inv * Wlin[c * 2 + oc];
    outp[b * 2 + oc] = s;
}

// ================= workspace layout =================
// floats
static constexpr size_t OFF_OUT   = 0;                        // [N*HC]
static constexpr size_t OFF_AS    = OFF_OUT + (size_t)NN*HC;  // [N*2]
static constexpr size_t OFF_AD    = OFF_AS  + (size_t)NN*HH;
static constexpr size_t OFF_ST1   = OFF_AD  + (size_t)NN*HH;  // zero from here: [2*64*128]
static constexpr size_t OFF_ST2   = OFF_ST1 + 2*64*128;
static constexpr size_t OFF_SC1   = OFF_ST2 + 2*64*128;       // [128]
static constexpr size_t OFF_SH1   = OFF_SC1 + 128;
static constexpr size_t OFF_SC2   = OFF_SH1 + 128;
static constexpr size_t OFF_SH2   = OFF_SC2 + 128;
static constexpr size_t OFF_POOL  = OFF_SH2 + 128;            // [B*HC]
static constexpr size_t OFF_CNT   = OFF_POOL+ (size_t)BB*HC;  // [B]
static constexpr size_t OFF_ZEND  = OFF_CNT + BB;             // end of zeroed float region
// ints (after float region) — deg FIRST so one memset covers floats+deg
static constexpr size_t IOFF_DEG  = 0;                        // [N]  (zeroed)
static constexpr size_t IOFF_ROWP = IOFF_DEG  + NN;           // [N+1]
static constexpr size_t IOFF_CUR  = IOFF_ROWP + NN + 1;       // [N]
static constexpr size_t IOFF_BSUM = IOFF_CUR  + NN;           // [NBLK_SCAN]
static constexpr size_t IOFF_BOFS = IOFF_BSUM + NBLK_SCAN;    // [NBLK_SCAN]
static constexpr size_t IOFF_ESRC = IOFF_BOFS + NBLK_SCAN;    // [ETOT]
static constexpr size_t IOFF_HB   = (IOFF_ESRC + ETOT + 3) & ~(size_t)3;  // [N*64] uints
static constexpr size_t IOFF_WF1  = IOFF_HB + (size_t)NN*64;  // [512*64] ints
static constexpr size_t IOFF_WF2  = IOFF_WF1 + (size_t)IN_C*64; // [128*64] ints
static constexpr size_t IOFF_END  = IOFF_WF2 + (size_t)HC*64;

extern "C" void kernel_launch(void* const* d_in, const int* in_sizes, int n_in,
                              void* d_out, int out_size, void* d_ws, size_t ws_size,
                              hipStream_t stream)
{
    const float* x       = (const float*)d_in[0];
    const int*   ei      = (const int*)  d_in[1];
    const int*   batch   = (const int*)  d_in[2];
    const float* W1      = (const float*)d_in[3];
    const float* atts1   = (const float*)d_in[4];
    const float* attd1   = (const float*)d_in[5];
    const float* gamma1  = (const float*)d_in[7];
    const float* beta1   = (const float*)d_in[8];
    const float* W2      = (const float*)d_in[9];
    const float* atts2   = (const float*)d_in[10];
    const float* attd2   = (const float*)d_in[11];
    const float* gamma2  = (const float*)d_in[13];
    const float* beta2   = (const float*)d_in[14];
    const float* Wlin    = (const float*)d_in[15];
    const float* blin    = (const float*)d_in[16];
    float* outp = (float*)d_out;

    float* ws    = (float*)d_ws;
    float* out   = ws + OFF_OUT;
    float* as_   = ws + OFF_AS;
    float* ad_   = ws + OFF_AD;
    float* st1   = ws + OFF_ST1;
    float* st2   = ws + OFF_ST2;
    float* sc1   = ws + OFF_SC1;
    float* sh1   = ws + OFF_SH1;
    float* sc2   = ws + OFF_SC2;
    float* sh2   = ws + OFF_SH2;
    float* pool  = ws + OFF_POOL;
    float* cnt   = ws + OFF_CNT;

    int* iws  = (int*)(ws + OFF_ZEND);
    int* deg  = iws + IOFF_DEG;
    int* rowp = iws + IOFF_ROWP;
    int* curp = iws + IOFF_CUR;
    int* bsum = iws + IOFF_BSUM;
    int* bofs = iws + IOFF_BOFS;
    int* esrc = iws + IOFF_ESRC;
    unsigned* hb = (unsigned*)(iws + IOFF_HB);
    unsigned short* Wf1 = (unsigned short*)(iws + IOFF_WF1);
    unsigned short* Wf2 = (unsigned short*)(iws + IOFF_WF2);

    const int BIN_BLK   = NXCD * NSLOT;          // 8 * 416 = 3328
    const int GEMM_BLK  = (NN + 63) / 64;        // 782: 64 rows x 128 cols
    const int WAVE_BLK  = NN / 8;                // 6250: 8 nodes/block (2 per wave)
    const int POOL_BLK  = (NN + 63) / 64;        // 782: 64 rows/block

    // single memset: bn-stats/sc-sh/pool/cnt float region + deg (contiguous)
    hipMemsetAsync(st1, 0, (OFF_ZEND - OFF_ST1) * sizeof(float) + NN * sizeof(int), stream);

    // ----- weight fragment packs + CSR build (fused prep; shared by both layers) -----
    prep_kernel<<<WFRG_BLKS + BIN_BLK, 256, 0, stream>>>(W1, Wf1, W2, Wf2, ei, deg);
    bsum_kernel<<<NBLK_SCAN, 256, 0, stream>>>(deg, bsum);
    bscan_kernel<<<1, 256, 0, stream>>>(bsum, bofs, rowp);
    bapply_kernel<<<NBLK_SCAN, 256, 0, stream>>>(deg, bofs, rowp, curp);
    scatter_kernel<<<BIN_BLK, 256, 0, stream>>>(ei, curp, esrc);

    // ----- layer 1 (GEMM + fused alpha + bf16 pack; agg + fused BN stats) -----
    mfma_gemm_kernel<IN_C, false><<<GEMM_BLK, 256, 0, stream>>>(
        x, Wf1, atts1, attd1, hb, as_, ad_, nullptr, nullptr);
    gat_agg_kernel<<<WAVE_BLK, 256, 0, stream>>>(rowp, esrc, as_, ad_, hb, out, st1);
    bn_params_kernel<<<1, 128, 0, stream>>>(st1, gamma1, beta1, sc1, sh1);

    // ----- layer 2 (BN1-affine+ReLU fused into GEMM2 A-load) -----
    mfma_gemm_kernel<HC, true><<<GEMM_BLK, 256, 0, stream>>>(
        out, Wf2, atts2, attd2, hb, as_, ad_, sc1, sh1);
    gat_agg_kernel<<<WAVE_BLK, 256, 0, stream>>>(rowp, esrc, as_, ad_, hb, out, st2);
    bn_params_kernel<<<1, 128, 0, stream>>>(st2, gamma2, beta2, sc2, sh2);

    // ----- pool + final linear -----
    pool_kernel<<<POOL_BLK, 256, 0, stream>>>(out, sc2, sh2, batch, pool, cnt);
    final_kernel<<<1, 128, 0, stream>>>(pool, cnt, Wlin, blin, outp);
}